// Round 7
// baseline (1319.537 us; speedup 1.0000x reference)
//
#include <hip/hip_runtime.h>
#include <cmath>

// ---------------- problem constants ----------------
constexpr int IMH = 320, IMW = 320, NPIX = IMH * IMW, NC = 21;
constexpr int CP4 = 6;           // padded channels / 4  (24 floats per row)
constexpr int DB = 5, DB1 = 6;   // bilateral lattice dim
constexpr int DS = 2, DS1 = 3;   // spatial lattice dim
constexpr int RB = NPIX * DB1;   // splat entries (bilateral) = 614400
constexpr int RS = NPIX * DS1;   // (spatial) = 307200
constexpr int TBS = 1 << 20;     // hash table slots (bilateral)
constexpr int TSS = 1 << 18;     // hash table slots (spatial)
constexpr int NBUCK = 1 << 16;   // spatial-sort buckets (c0,c1 low bytes)

#define EMPTY_KEY 0xFFFFFFFFFFFFFFFFULL

__device__ __forceinline__ unsigned long long mix64(unsigned long long x) {
    x ^= x >> 33; x *= 0xff51afd7ed558ccdULL;
    x ^= x >> 33; x *= 0xc4ceb9fe1a85ec53ULL;
    x ^= x >> 33; return x;
}

// XCD-aware block swizzle (used ONLY in grid-stride kernels with gridDim%8==0,
// where it is a provable bijection on [0,gridDim)): round-robin block->XCD
// dispatch becomes a contiguous index chunk per XCD.
__device__ __forceinline__ int swz_block() {
    int g = gridDim.x >> 3;
    return (blockIdx.x & 7) * g + (blockIdx.x >> 3);
}

// ---------------- permutohedral embedding (matches reference op-for-op, f32) ----------------
template<int D>
__device__ void perm_embed(const float* f, float* bary, unsigned long long* pk) {
    constexpr int D1 = D + 1;
    float cf[D];
    #pragma unroll
    for (int i = 0; i < D; i++) {
        double s = sqrt(2.0 / 3.0) * (double)D1 / sqrt((double)((i + 1) * (i + 2)));
        cf[i] = f[i] * (float)s;
    }
    float csum[D];
    float acc = 0.f;
    #pragma unroll
    for (int i = D - 1; i >= 0; i--) { acc += cf[i]; csum[i] = acc; }
    float el[D1];
    el[0] = csum[0];
    #pragma unroll
    for (int i = 1; i < D; i++) el[i] = csum[i] - (float)i * cf[i - 1];
    el[D] = -(float)D * cf[D - 1];
    const float down = 1.0f / (float)D1;
    float rem0[D1]; int rank[D1]; int ssum = 0;
    #pragma unroll
    for (int i = 0; i < D1; i++) {
        float rd = rintf(el[i] * down);
        rem0[i] = rd * (float)D1;
        ssum += (int)rd;
    }
    float diff[D1];
    #pragma unroll
    for (int i = 0; i < D1; i++) diff[i] = el[i] - rem0[i];
    #pragma unroll
    for (int i = 0; i < D1; i++) {
        int r = 0;
        #pragma unroll
        for (int j = 0; j < D1; j++)
            r += (diff[j] > diff[i]) || ((diff[j] == diff[i]) && (j < i));
        rank[i] = r + ssum;
    }
    #pragma unroll
    for (int i = 0; i < D1; i++) {
        if (rank[i] < 0)      { rank[i] += D1; rem0[i] += (float)D1; }
        else if (rank[i] > D) { rank[i] -= D1; rem0[i] -= (float)D1; }
    }
    float b[D + 2];
    #pragma unroll
    for (int i = 0; i < D + 2; i++) b[i] = 0.f;
    #pragma unroll
    for (int i = 0; i < D1; i++) b[D - rank[i]]     += (el[i] - rem0[i]) * down;
    #pragma unroll
    for (int i = 0; i < D1; i++) b[D + 1 - rank[i]] -= (el[i] - rem0[i]) * down;
    b[0] += 1.0f + b[D + 1];
    #pragma unroll
    for (int i = 0; i < D1; i++) bary[i] = b[i];
    int key0[D];
    #pragma unroll
    for (int i = 0; i < D; i++) key0[i] = (int)rintf(rem0[i]);
    #pragma unroll
    for (int r = 0; r < D1; r++) {
        unsigned long long p = 0;
        #pragma unroll
        for (int i = 0; i < D; i++) {
            int c = key0[i] + ((rank[i] < D1 - r) ? r : r - D1);
            p |= ((unsigned long long)((unsigned)(c + 2048) & 0xFFFu)) << (12 * i);
        }
        pk[r] = p;
    }
}

// ---------------- hash table ----------------
__device__ __forceinline__ int hash_insert(unsigned long long* hk, int tmask, unsigned long long k) {
    int slot = (int)(mix64(k) & (unsigned long long)tmask);
    while (true) {
        unsigned long long prev = atomicCAS(&hk[slot], EMPTY_KEY, k);
        if (prev == EMPTY_KEY || prev == k) return slot;
        slot = (slot + 1) & tmask;
    }
}
__device__ __forceinline__ int hash_lookup(const unsigned long long* hk, const int* hid,
                                           int tmask, unsigned long long k) {
    int slot = (int)(mix64(k) & (unsigned long long)tmask);
    while (true) {
        unsigned long long v = hk[slot];
        if (v == k) return hid[slot];
        if (v == EMPTY_KEY) return -1;
        slot = (slot + 1) & tmask;
    }
}

// bucket code from low bytes of first two (biased) lattice coords; +2048 bias
// vanishes mod 256, so adjacent coords -> adjacent buckets.
__device__ __forceinline__ int key_code(unsigned long long k) {
    int c0 = (int)(k & 0xFFFULL);
    int c1 = (int)((k >> 12) & 0xFFFULL);
    return ((c0 & 0xFF) << 8) | (c1 & 0xFF);
}

// ---------------- build kernels ----------------
__global__ void build_bilateral(const float* __restrict__ image, unsigned long long* hk,
                                int tmask, int* os, float* wsv) {
    int i = blockIdx.x * blockDim.x + threadIdx.x;
    if (i >= NPIX) return;
    int x = i % IMW, y = i / IMW;
    float f[DB];
    f[0] = (float)x / 80.0f;           // THETA_ALPHA
    f[1] = (float)y / 80.0f;
    f[2] = image[i * 3 + 0] / 13.0f;   // THETA_BETA
    f[3] = image[i * 3 + 1] / 13.0f;
    f[4] = image[i * 3 + 2] / 13.0f;
    float bary[DB1]; unsigned long long pk[DB1];
    perm_embed<DB>(f, bary, pk);
    #pragma unroll
    for (int r = 0; r < DB1; r++) {
        wsv[i * DB1 + r] = bary[r];
        os[i * DB1 + r] = hash_insert(hk, tmask, pk[r]);  // slot; remapped to id later
    }
}

__global__ void build_spatial(unsigned long long* hk, int tmask, int* os, float* wsv) {
    int i = blockIdx.x * blockDim.x + threadIdx.x;
    if (i >= NPIX) return;
    int x = i % IMW, y = i / IMW;
    float f[DS];
    f[0] = (float)x / 3.0f;            // THETA_GAMMA
    f[1] = (float)y / 3.0f;
    float bary[DS1]; unsigned long long pk[DS1];
    perm_embed<DS>(f, bary, pk);
    #pragma unroll
    for (int r = 0; r < DS1; r++) {
        wsv[i * DS1 + r] = bary[r];
        os[i * DS1 + r] = hash_insert(hk, tmask, pk[r]);
    }
}

// ---------------- barrier-free scan machinery ----------------
__global__ void scan_wave_partial(const int* __restrict__ count, int* incl, int* wsum, int n) {
    int idx = blockIdx.x * blockDim.x + threadIdx.x;
    int lane = threadIdx.x & 63;
    int v = (idx < n) ? count[idx] : 0;
    int s = v;
    #pragma unroll
    for (int d = 1; d < 64; d <<= 1) {
        int t = __shfl_up(s, d);
        if (lane >= d) s += t;
    }
    if (idx < n) incl[idx] = s;
    if (lane == 63) wsum[idx >> 6] = s;
}

__global__ void scan_partials_excl(int* w, int nw, int* total_out) {
    __shared__ int sh[256];
    __shared__ int run;
    if (threadIdx.x == 0) run = 0;
    __syncthreads();
    for (int basei = 0; basei < nw; basei += 256) {
        int idx = basei + threadIdx.x;
        int v = (idx < nw) ? w[idx] : 0;
        sh[threadIdx.x] = v;
        __syncthreads();
        for (int d = 1; d < 256; d <<= 1) {
            int t = (threadIdx.x >= d) ? sh[threadIdx.x - d] : 0;
            __syncthreads();
            sh[threadIdx.x] += t;
            __syncthreads();
        }
        int total = sh[255];
        if (idx < nw) w[idx] = run + sh[threadIdx.x] - v;
        __syncthreads();
        if (threadIdx.x == 0) run += total;
        __syncthreads();
    }
    if (total_out != nullptr && threadIdx.x == 0) *total_out = run;
}

__global__ void scan_finalize(int* off, const int* __restrict__ count,
                              const int* __restrict__ wsum, int n) {
    int idx = blockIdx.x * blockDim.x + threadIdx.x;
    if (idx < n) off[idx] = off[idx] - count[idx] + wsum[idx >> 6];
}

// ---------------- bucket-sorted compaction ----------------
__global__ void hist_keys(const unsigned long long* __restrict__ hk, int* hist, int T) {
    int s = blockIdx.x * blockDim.x + threadIdx.x;
    if (s >= T) return;
    unsigned long long k = hk[s];
    if (k != EMPTY_KEY) atomicAdd(&hist[key_code(k)], 1);
}

__global__ void assign_ids(const unsigned long long* __restrict__ hk, int* hid,
                           const int* __restrict__ histOff, int* histFill,
                           unsigned long long* uk, int T) {
    int s = blockIdx.x * blockDim.x + threadIdx.x;
    if (s >= T) return;
    unsigned long long k = hk[s];
    if (k == EMPTY_KEY) return;
    int code = key_code(k);
    int id = histOff[code] + atomicAdd(&histFill[code], 1);
    hid[s] = id;
    uk[id] = k;
}

__global__ void os_count_fused(int* os, const int* __restrict__ hid, int* count, int R) {
    int i = blockIdx.x * blockDim.x + threadIdx.x;
    if (i >= R) return;
    int id = hid[os[i]];
    os[i] = id;
    atomicAdd(&count[id], 1);
}

template<int D>
__global__ void build_neighbors(const unsigned long long* __restrict__ uk,
                                const unsigned long long* __restrict__ hk,
                                const int* __restrict__ hid,
                                int tmask, const int* cnt, int stride,
                                int* n1, int* n2) {
    int m = blockIdx.x * blockDim.x + threadIdx.x;
    if (m >= *cnt) return;
    unsigned long long k = uk[m];
    int c[D];
    #pragma unroll
    for (int i = 0; i < D; i++) c[i] = (int)((k >> (12 * i)) & 0xFFFULL) - 2048;
    for (int j = 0; j <= D; j++) {
        unsigned long long p1 = 0, p2 = 0;
        #pragma unroll
        for (int i = 0; i < D; i++) {
            int a = c[i] + ((i == j) ? D : -1);   // key - 1 + (D+1)*e_j
            int b = c[i] + ((i == j) ? -D : 1);   // key + 1 - (D+1)*e_j
            p1 |= ((unsigned long long)((unsigned)(a + 2048) & 0xFFFu)) << (12 * i);
            p2 |= ((unsigned long long)((unsigned)(b + 2048) & 0xFFFu)) << (12 * i);
        }
        n1[j * stride + m] = hash_lookup(hk, hid, tmask, p1);
        n2[j * stride + m] = hash_lookup(hk, hid, tmask, p2);
    }
}

template<int D1>
__global__ void fill_entries(const int* __restrict__ os, const float* __restrict__ wsv,
                             const int* __restrict__ off, int* fill, int2* epw, int R) {
    int idx = blockIdx.x * blockDim.x + threadIdx.x;
    if (idx >= R) return;
    int m = os[idx];
    int pos = off[m] + atomicAdd(&fill[m], 1);
    epw[pos] = make_int2(idx / D1, __float_as_int(wsv[idx]));
}

// ---------------- filter kernels (float4, padded C=24) ----------------
__global__ void gather_splat4(const float4* __restrict__ Qp, const int* __restrict__ off,
                              const int* __restrict__ count, const int2* __restrict__ epw,
                              float4* __restrict__ buf, const int* cnt) {
    int M = *cnt;
    int total = (M + 1) * CP4;
    int stride = gridDim.x * blockDim.x;
    for (int idx = swz_block() * blockDim.x + threadIdx.x; idx < total; idx += stride) {
        int row = idx / CP4, c4 = idx - row * CP4;
        float4 acc = make_float4(0.f, 0.f, 0.f, 0.f);
        if (row > 0) {
            int m = row - 1;
            int s = off[m], e = s + count[m];
            for (int t = s; t < e; t++) {
                int2 pw = epw[t];
                float w = __int_as_float(pw.y);
                float4 v = Qp[(size_t)pw.x * CP4 + c4];
                acc.x += w * v.x; acc.y += w * v.y; acc.z += w * v.z; acc.w += w * v.w;
            }
        }
        buf[idx] = acc;
    }
}

__global__ void gather_splat1(const int* __restrict__ off, const int* __restrict__ count,
                              const int2* __restrict__ epw, float* __restrict__ buf,
                              const int* cnt) {
    int M = *cnt;
    int stride = gridDim.x * blockDim.x;
    for (int row = blockIdx.x * blockDim.x + threadIdx.x; row <= M; row += stride) {
        if (row == 0) { buf[0] = 0.f; continue; }
        int m = row - 1;
        int s = off[m], e = s + count[m];
        float acc = 0.f;
        for (int t = s; t < e; t++) acc += __int_as_float(epw[t].y);
        buf[row] = acc;
    }
}

__global__ void blur4(const float4* __restrict__ in, float4* __restrict__ out,
                      const int* __restrict__ n1, const int* __restrict__ n2,
                      const int* cnt) {
    int M = *cnt;
    int total = (M + 1) * CP4;
    int stride = gridDim.x * blockDim.x;
    for (int idx = swz_block() * blockDim.x + threadIdx.x; idx < total; idx += stride) {
        int row = idx / CP4, c4 = idx - row * CP4;
        if (row == 0) { out[idx] = make_float4(0.f, 0.f, 0.f, 0.f); continue; }
        int m = row - 1;
        float4 a = in[(size_t)(n1[m] + 1) * CP4 + c4];
        float4 b = in[(size_t)(n2[m] + 1) * CP4 + c4];
        float4 x = in[idx];
        x.x += 0.5f * (a.x + b.x); x.y += 0.5f * (a.y + b.y);
        x.z += 0.5f * (a.z + b.z); x.w += 0.5f * (a.w + b.w);
        out[idx] = x;
    }
}

__global__ void blur1(const float* __restrict__ in, float* __restrict__ out,
                      const int* __restrict__ n1, const int* __restrict__ n2,
                      const int* cnt) {
    int M = *cnt;
    int stride = gridDim.x * blockDim.x;
    for (int row = blockIdx.x * blockDim.x + threadIdx.x; row <= M; row += stride) {
        if (row == 0) { out[0] = 0.f; continue; }
        int m = row - 1;
        out[row] = in[row] + 0.5f * (in[n1[m] + 1] + in[n2[m] + 1]);
    }
}

// fused slice(bilateral)+slice(spatial)+normalize -> one padded msg array
__global__ void slice_msg(const float4* __restrict__ bufb, const int* __restrict__ osb,
                          const float* __restrict__ wsb,
                          const float4* __restrict__ bufs, const int* __restrict__ oss,
                          const float* __restrict__ wss,
                          const float* __restrict__ nbv, const float* __restrict__ nsv,
                          float4* __restrict__ msgp, float alphaB, float alphaS) {
    int idx = blockIdx.x * blockDim.x + threadIdx.x;
    if (idx >= NPIX * CP4) return;
    int i = idx / CP4, c4 = idx - i * CP4;
    float4 sb = make_float4(0.f, 0.f, 0.f, 0.f);
    #pragma unroll
    for (int r = 0; r < DB1; r++) {
        float w = wsb[i * DB1 + r];
        float4 v = bufb[(size_t)(osb[i * DB1 + r] + 1) * CP4 + c4];
        sb.x += w * v.x; sb.y += w * v.y; sb.z += w * v.z; sb.w += w * v.w;
    }
    float4 ss = make_float4(0.f, 0.f, 0.f, 0.f);
    #pragma unroll
    for (int r = 0; r < DS1; r++) {
        float w = wss[i * DS1 + r];
        float4 v = bufs[(size_t)(oss[i * DS1 + r] + 1) * CP4 + c4];
        ss.x += w * v.x; ss.y += w * v.y; ss.z += w * v.z; ss.w += w * v.w;
    }
    float ib = 10.0f * alphaB / nbv[i];
    float is = 3.0f * alphaS / nsv[i];
    float4 msg;
    msg.x = ib * sb.x + is * ss.x;
    msg.y = ib * sb.y + is * ss.y;
    msg.z = ib * sb.z + is * ss.z;
    msg.w = ib * sb.w + is * ss.w;
    msgp[idx] = msg;
}

template<int D1>
__global__ void slice_norm(const float* __restrict__ buf, const int* __restrict__ os,
                           const float* __restrict__ wsv, float* normv, float alpha) {
    int i = blockIdx.x * blockDim.x + threadIdx.x;
    if (i >= NPIX) return;
    float s = 0.f;
    #pragma unroll
    for (int r = 0; r < D1; r++)
        s += wsv[i * D1 + r] * buf[os[i * D1 + r] + 1];
    normv[i] = alpha * s + 1e-20f;
}

// Q (d_out, 21/pixel) + Qp (padded 24/pixel, zero tail) written together
__global__ void update_q(const float* __restrict__ U, const float4* __restrict__ msgp,
                         float* __restrict__ Q, float4* __restrict__ Qp, int use_msg) {
    int i = blockIdx.x * blockDim.x + threadIdx.x;
    if (i >= NPIX) return;
    float msg[24];
    if (use_msg) {
        #pragma unroll
        for (int t = 0; t < CP4; t++) {
            float4 a = msgp[i * CP4 + t];
            msg[4 * t + 0] = a.x; msg[4 * t + 1] = a.y;
            msg[4 * t + 2] = a.z; msg[4 * t + 3] = a.w;
        }
    } else {
        #pragma unroll
        for (int t = 0; t < 24; t++) msg[t] = 0.f;
    }
    float l[NC];
    float mx = -1e30f;
    #pragma unroll
    for (int c = 0; c < NC; c++) {
        float v = -U[i * NC + c] + msg[c];
        l[c] = v; mx = fmaxf(mx, v);
    }
    float s = 0.f;
    #pragma unroll
    for (int c = 0; c < NC; c++) { float e = expf(l[c] - mx); l[c] = e; s += e; }
    float inv = 1.0f / s;
    float q[24];
    #pragma unroll
    for (int c = 0; c < NC; c++) {
        q[c] = l[c] * inv;
        Q[i * NC + c] = q[c];
    }
    q[21] = 0.f; q[22] = 0.f; q[23] = 0.f;
    #pragma unroll
    for (int t = 0; t < CP4; t++)
        Qp[i * CP4 + t] = make_float4(q[4 * t], q[4 * t + 1], q[4 * t + 2], q[4 * t + 3]);
}

// ---------------- host orchestration ----------------
extern "C" void kernel_launch(void* const* d_in, const int* in_sizes, int n_in,
                              void* d_out, int out_size, void* d_ws, size_t ws_size,
                              hipStream_t stream) {
    const float* U     = (const float*)d_in[0];
    const float* image = (const float*)d_in[1];
    float* Q = (float*)d_out;

    char* base = (char*)d_ws;
    size_t off = 0;
    auto alloc = [&](size_t bytes) -> void* {
        off = (off + 255) & ~(size_t)255;
        void* p = base + off; off += bytes; return p;
    };
    int*   os_b = (int*)  alloc((size_t)RB * 4);
    float* ws_b = (float*)alloc((size_t)RB * 4);
    int*   n1_b = (int*)  alloc((size_t)DB1 * RB * 4);
    int*   n2_b = (int*)  alloc((size_t)DB1 * RB * 4);
    unsigned long long* uk_b = (unsigned long long*)alloc((size_t)RB * 8);
    int*   os_s = (int*)  alloc((size_t)RS * 4);
    float* ws_s = (float*)alloc((size_t)RS * 4);
    int*   n1_s = (int*)  alloc((size_t)DS1 * RS * 4);
    int*   n2_s = (int*)  alloc((size_t)DS1 * RS * 4);
    unsigned long long* uk_s = (unsigned long long*)alloc((size_t)RS * 8);
    unsigned long long* hk = (unsigned long long*)alloc((size_t)TBS * 8);
    int*   hid  = (int*)  alloc((size_t)TBS * 4);
    int*   cnt  = (int*)  alloc(256);   // [0]=M_b, [1]=M_s
    int*   hist     = (int*)alloc((size_t)NBUCK * 4);
    int*   histOff  = (int*)alloc((size_t)NBUCK * 4);
    int*   histFill = (int*)alloc((size_t)NBUCK * 4);
    int*   wsums    = (int*)alloc((size_t)(RB / 64) * 4);
    int*   cntr_b = (int*)  alloc((size_t)RB * 4);
    int*   off_b  = (int*)  alloc((size_t)RB * 4);
    int*   fill_b = (int*)  alloc((size_t)RB * 4);
    int2*  epw_b  = (int2*) alloc((size_t)RB * 8);
    int*   cntr_s = (int*)  alloc((size_t)RS * 4);
    int*   off_s  = (int*)  alloc((size_t)RS * 4);
    int*   fill_s = (int*)  alloc((size_t)RS * 4);
    int2*  epw_s  = (int2*) alloc((size_t)RS * 8);
    float* norm_b = (float*)alloc((size_t)NPIX * 4);
    float* norm_s = (float*)alloc((size_t)NPIX * 4);
    float4* Qp   = (float4*)alloc((size_t)NPIX * CP4 * 16);
    float4* msgp = (float4*)alloc((size_t)NPIX * CP4 * 16);
    float4* buf0 = (float4*)alloc((size_t)(RB + 1) * CP4 * 16);
    float4* buf1 = (float4*)alloc((size_t)(RB + 1) * CP4 * 16);
    if (off > ws_size) return;

    const float ALPHA_B = (float)(1.0 / (1.0 + exp2(-(double)DB)));  // 32/33
    const float ALPHA_S = (float)(1.0 / (1.0 + exp2(-(double)DS)));  // 4/5

    constexpr int PG = 4096;

    hipMemsetAsync(cnt, 0, 16, stream);

    // ---- build bilateral lattice ----
    hipMemsetAsync(hk, 0xFF, (size_t)TBS * 8, stream);
    hipMemsetAsync(cntr_b, 0, (size_t)RB * 4, stream);
    hipMemsetAsync(fill_b, 0, (size_t)RB * 4, stream);
    hipMemsetAsync(hist, 0, (size_t)NBUCK * 4, stream);
    hipMemsetAsync(histFill, 0, (size_t)NBUCK * 4, stream);
    build_bilateral<<<(NPIX + 255) / 256, 256, 0, stream>>>(image, hk, TBS - 1, os_b, ws_b);
    hist_keys<<<TBS / 256, 256, 0, stream>>>(hk, hist, TBS);
    scan_wave_partial<<<NBUCK / 256, 256, 0, stream>>>(hist, histOff, wsums, NBUCK);
    scan_partials_excl<<<1, 256, 0, stream>>>(wsums, NBUCK / 64, cnt + 0);
    scan_finalize<<<NBUCK / 256, 256, 0, stream>>>(histOff, hist, wsums, NBUCK);
    assign_ids<<<TBS / 256, 256, 0, stream>>>(hk, hid, histOff, histFill, uk_b, TBS);
    os_count_fused<<<(RB + 255) / 256, 256, 0, stream>>>(os_b, hid, cntr_b, RB);
    build_neighbors<DB><<<(RB + 255) / 256, 256, 0, stream>>>(uk_b, hk, hid, TBS - 1, cnt + 0, RB, n1_b, n2_b);
    scan_wave_partial<<<RB / 256, 256, 0, stream>>>(cntr_b, off_b, wsums, RB);
    scan_partials_excl<<<1, 256, 0, stream>>>(wsums, RB / 64, nullptr);
    scan_finalize<<<RB / 256, 256, 0, stream>>>(off_b, cntr_b, wsums, RB);
    fill_entries<DB1><<<(RB + 255) / 256, 256, 0, stream>>>(os_b, ws_b, off_b, fill_b, epw_b, RB);

    // ---- build spatial lattice (reuse hash region, smaller table) ----
    hipMemsetAsync(hk, 0xFF, (size_t)TSS * 8, stream);
    hipMemsetAsync(cntr_s, 0, (size_t)RS * 4, stream);
    hipMemsetAsync(fill_s, 0, (size_t)RS * 4, stream);
    hipMemsetAsync(hist, 0, (size_t)NBUCK * 4, stream);
    hipMemsetAsync(histFill, 0, (size_t)NBUCK * 4, stream);
    build_spatial<<<(NPIX + 255) / 256, 256, 0, stream>>>(hk, TSS - 1, os_s, ws_s);
    hist_keys<<<TSS / 256, 256, 0, stream>>>(hk, hist, TSS);
    scan_wave_partial<<<NBUCK / 256, 256, 0, stream>>>(hist, histOff, wsums, NBUCK);
    scan_partials_excl<<<1, 256, 0, stream>>>(wsums, NBUCK / 64, cnt + 1);
    scan_finalize<<<NBUCK / 256, 256, 0, stream>>>(histOff, hist, wsums, NBUCK);
    assign_ids<<<TSS / 256, 256, 0, stream>>>(hk, hid, histOff, histFill, uk_s, TSS);
    os_count_fused<<<(RS + 255) / 256, 256, 0, stream>>>(os_s, hid, cntr_s, RS);
    build_neighbors<DS><<<(RS + 255) / 256, 256, 0, stream>>>(uk_s, hk, hid, TSS - 1, cnt + 1, RS, n1_s, n2_s);
    scan_wave_partial<<<RS / 256, 256, 0, stream>>>(cntr_s, off_s, wsums, RS);
    scan_partials_excl<<<1, 256, 0, stream>>>(wsums, RS / 64, nullptr);
    scan_finalize<<<RS / 256, 256, 0, stream>>>(off_s, cntr_s, wsums, RS);
    fill_entries<DS1><<<(RS + 255) / 256, 256, 0, stream>>>(os_s, ws_s, off_s, fill_s, epw_s, RS);

    // ---- norm filters (C=1), computed once ----
    {
        float* nb0 = (float*)buf0; float* nb1 = (float*)buf1;
        gather_splat1<<<1024, 256, 0, stream>>>(off_b, cntr_b, epw_b, nb0, cnt + 0);
        float* a = nb0; float* b = nb1;
        for (int j = 0; j < DB1; j++) {
            blur1<<<1024, 256, 0, stream>>>(a, b, n1_b + (size_t)j * RB, n2_b + (size_t)j * RB, cnt + 0);
            float* t = a; a = b; b = t;
        }
        slice_norm<DB1><<<(NPIX + 255) / 256, 256, 0, stream>>>(a, os_b, ws_b, norm_b, ALPHA_B);

        gather_splat1<<<1024, 256, 0, stream>>>(off_s, cntr_s, epw_s, nb0, cnt + 1);
        a = nb0; b = nb1;
        for (int j = 0; j < DS1; j++) {
            blur1<<<1024, 256, 0, stream>>>(a, b, n1_s + (size_t)j * RS, n2_s + (size_t)j * RS, cnt + 1);
            float* t = a; a = b; b = t;
        }
        slice_norm<DS1><<<(NPIX + 255) / 256, 256, 0, stream>>>(a, os_s, ws_s, norm_s, ALPHA_S);
    }

    // ---- Q0 = softmax(-U) ----
    update_q<<<(NPIX + 255) / 256, 256, 0, stream>>>(U, msgp, Q, Qp, 0);

    // ---- 5 mean-field iterations ----
    for (int it = 0; it < 5; it++) {
        // bilateral: gather into buf0; 6 blurs buf0->buf1->...->buf0 (result buf0)
        gather_splat4<<<PG, 256, 0, stream>>>(Qp, off_b, cntr_b, epw_b, buf0, cnt + 0);
        float4* a = buf0; float4* b = buf1;
        for (int j = 0; j < DB1; j++) {
            blur4<<<PG, 256, 0, stream>>>(a, b, n1_b + (size_t)j * RB, n2_b + (size_t)j * RB, cnt + 0);
            float4* t = a; a = b; b = t;
        }
        float4* resB = a;   // buf0 after 6 swaps

        // spatial: gather into msgp; 3 blurs msgp->buf1->msgp->buf1 (result buf1).
        // buf1 only held the j=4 bilateral intermediate — free to reuse.
        gather_splat4<<<PG, 256, 0, stream>>>(Qp, off_s, cntr_s, epw_s, msgp, cnt + 1);
        float4* c = msgp; float4* d = buf1;
        for (int j = 0; j < DS1; j++) {
            blur4<<<PG, 256, 0, stream>>>(c, d, n1_s + (size_t)j * RS, n2_s + (size_t)j * RS, cnt + 1);
            float4* t = c; c = d; d = t;
        }
        float4* resS = c;   // buf1 after 3 swaps — no aliasing with msgp below

        // fused slices + normalization -> msgp (writes all NPIX*CP4)
        slice_msg<<<(NPIX * CP4 + 255) / 256, 256, 0, stream>>>(
            resB, os_b, ws_b, resS, os_s, ws_s, norm_b, norm_s, msgp, ALPHA_B, ALPHA_S);

        // Q = softmax(-U + msg)
        update_q<<<(NPIX + 255) / 256, 256, 0, stream>>>(U, msgp, Q, Qp, 1);
    }
}

// Round 8
// 1271.932 us; speedup vs baseline: 1.0374x; 1.0374x over previous
//
#include <hip/hip_runtime.h>
#include <cmath>

// ---------------- problem constants ----------------
constexpr int IMH = 320, IMW = 320, NPIX = IMH * IMW, NC = 21;
constexpr int CP4 = 6;           // padded channels / 4  (24 floats per row)
constexpr int DB = 5, DB1 = 6;   // bilateral lattice dim
constexpr int DS = 2, DS1 = 3;   // spatial lattice dim
constexpr int RB = NPIX * DB1;   // splat entries (bilateral) = 614400
constexpr int RS = NPIX * DS1;   // (spatial) = 307200
constexpr int TBS = 1 << 20;     // hash table slots (bilateral)
constexpr int TSS = 1 << 18;     // hash table slots (spatial)
constexpr int NBUCK = 1 << 16;   // spatial-sort buckets (c0,c1 low bytes)

#define EMPTY_KEY 0xFFFFFFFFFFFFFFFFULL

__device__ __forceinline__ unsigned long long mix64(unsigned long long x) {
    x ^= x >> 33; x *= 0xff51afd7ed558ccdULL;
    x ^= x >> 33; x *= 0xc4ceb9fe1a85ec53ULL;
    x ^= x >> 33; return x;
}

// NOTE: an XCD block swizzle ((b&7)*g + (b>>3)) was tried in r6/r7 and
// REGRESSED (gather_splat4 45->52us, occupancy 7.5%): block->XCD dispatch is
// not round-robin-by-blockIdx here, and for small-work grids the swizzle
// concentrates all active blocks onto 1/8 of the index space. Plain order wins.

// ---------------- permutohedral embedding (matches reference op-for-op, f32) ----------------
template<int D>
__device__ void perm_embed(const float* f, float* bary, unsigned long long* pk) {
    constexpr int D1 = D + 1;
    float cf[D];
    #pragma unroll
    for (int i = 0; i < D; i++) {
        double s = sqrt(2.0 / 3.0) * (double)D1 / sqrt((double)((i + 1) * (i + 2)));
        cf[i] = f[i] * (float)s;
    }
    float csum[D];
    float acc = 0.f;
    #pragma unroll
    for (int i = D - 1; i >= 0; i--) { acc += cf[i]; csum[i] = acc; }
    float el[D1];
    el[0] = csum[0];
    #pragma unroll
    for (int i = 1; i < D; i++) el[i] = csum[i] - (float)i * cf[i - 1];
    el[D] = -(float)D * cf[D - 1];
    const float down = 1.0f / (float)D1;
    float rem0[D1]; int rank[D1]; int ssum = 0;
    #pragma unroll
    for (int i = 0; i < D1; i++) {
        float rd = rintf(el[i] * down);
        rem0[i] = rd * (float)D1;
        ssum += (int)rd;
    }
    float diff[D1];
    #pragma unroll
    for (int i = 0; i < D1; i++) diff[i] = el[i] - rem0[i];
    #pragma unroll
    for (int i = 0; i < D1; i++) {
        int r = 0;
        #pragma unroll
        for (int j = 0; j < D1; j++)
            r += (diff[j] > diff[i]) || ((diff[j] == diff[i]) && (j < i));
        rank[i] = r + ssum;
    }
    #pragma unroll
    for (int i = 0; i < D1; i++) {
        if (rank[i] < 0)      { rank[i] += D1; rem0[i] += (float)D1; }
        else if (rank[i] > D) { rank[i] -= D1; rem0[i] -= (float)D1; }
    }
    float b[D + 2];
    #pragma unroll
    for (int i = 0; i < D + 2; i++) b[i] = 0.f;
    #pragma unroll
    for (int i = 0; i < D1; i++) b[D - rank[i]]     += (el[i] - rem0[i]) * down;
    #pragma unroll
    for (int i = 0; i < D1; i++) b[D + 1 - rank[i]] -= (el[i] - rem0[i]) * down;
    b[0] += 1.0f + b[D + 1];
    #pragma unroll
    for (int i = 0; i < D1; i++) bary[i] = b[i];
    int key0[D];
    #pragma unroll
    for (int i = 0; i < D; i++) key0[i] = (int)rintf(rem0[i]);
    #pragma unroll
    for (int r = 0; r < D1; r++) {
        unsigned long long p = 0;
        #pragma unroll
        for (int i = 0; i < D; i++) {
            int c = key0[i] + ((rank[i] < D1 - r) ? r : r - D1);
            p |= ((unsigned long long)((unsigned)(c + 2048) & 0xFFFu)) << (12 * i);
        }
        pk[r] = p;
    }
}

// ---------------- hash table ----------------
__device__ __forceinline__ int hash_insert(unsigned long long* hk, int tmask, unsigned long long k) {
    int slot = (int)(mix64(k) & (unsigned long long)tmask);
    while (true) {
        unsigned long long prev = atomicCAS(&hk[slot], EMPTY_KEY, k);
        if (prev == EMPTY_KEY || prev == k) return slot;
        slot = (slot + 1) & tmask;
    }
}
__device__ __forceinline__ int hash_lookup(const unsigned long long* hk, const int* hid,
                                           int tmask, unsigned long long k) {
    int slot = (int)(mix64(k) & (unsigned long long)tmask);
    while (true) {
        unsigned long long v = hk[slot];
        if (v == k) return hid[slot];
        if (v == EMPTY_KEY) return -1;
        slot = (slot + 1) & tmask;
    }
}

// bucket code from low bytes of first two (biased) lattice coords; +2048 bias
// vanishes mod 256, so adjacent coords -> adjacent buckets.
__device__ __forceinline__ int key_code(unsigned long long k) {
    int c0 = (int)(k & 0xFFFULL);
    int c1 = (int)((k >> 12) & 0xFFFULL);
    return ((c0 & 0xFF) << 8) | (c1 & 0xFF);
}

// ---------------- build kernels ----------------
__global__ void build_bilateral(const float* __restrict__ image, unsigned long long* hk,
                                int tmask, int* os, float* wsv) {
    int i = blockIdx.x * blockDim.x + threadIdx.x;
    if (i >= NPIX) return;
    int x = i % IMW, y = i / IMW;
    float f[DB];
    f[0] = (float)x / 80.0f;           // THETA_ALPHA
    f[1] = (float)y / 80.0f;
    f[2] = image[i * 3 + 0] / 13.0f;   // THETA_BETA
    f[3] = image[i * 3 + 1] / 13.0f;
    f[4] = image[i * 3 + 2] / 13.0f;
    float bary[DB1]; unsigned long long pk[DB1];
    perm_embed<DB>(f, bary, pk);
    #pragma unroll
    for (int r = 0; r < DB1; r++) {
        wsv[i * DB1 + r] = bary[r];
        os[i * DB1 + r] = hash_insert(hk, tmask, pk[r]);  // slot; remapped to id later
    }
}

__global__ void build_spatial(unsigned long long* hk, int tmask, int* os, float* wsv) {
    int i = blockIdx.x * blockDim.x + threadIdx.x;
    if (i >= NPIX) return;
    int x = i % IMW, y = i / IMW;
    float f[DS];
    f[0] = (float)x / 3.0f;            // THETA_GAMMA
    f[1] = (float)y / 3.0f;
    float bary[DS1]; unsigned long long pk[DS1];
    perm_embed<DS>(f, bary, pk);
    #pragma unroll
    for (int r = 0; r < DS1; r++) {
        wsv[i * DS1 + r] = bary[r];
        os[i * DS1 + r] = hash_insert(hk, tmask, pk[r]);
    }
}

// ---------------- barrier-free scan machinery ----------------
__global__ void scan_wave_partial(const int* __restrict__ count, int* incl, int* wsum, int n) {
    int idx = blockIdx.x * blockDim.x + threadIdx.x;
    int lane = threadIdx.x & 63;
    int v = (idx < n) ? count[idx] : 0;
    int s = v;
    #pragma unroll
    for (int d = 1; d < 64; d <<= 1) {
        int t = __shfl_up(s, d);
        if (lane >= d) s += t;
    }
    if (idx < n) incl[idx] = s;
    if (lane == 63) wsum[idx >> 6] = s;
}

__global__ void scan_partials_excl(int* w, int nw, int* total_out) {
    __shared__ int sh[256];
    __shared__ int run;
    if (threadIdx.x == 0) run = 0;
    __syncthreads();
    for (int basei = 0; basei < nw; basei += 256) {
        int idx = basei + threadIdx.x;
        int v = (idx < nw) ? w[idx] : 0;
        sh[threadIdx.x] = v;
        __syncthreads();
        for (int d = 1; d < 256; d <<= 1) {
            int t = (threadIdx.x >= d) ? sh[threadIdx.x - d] : 0;
            __syncthreads();
            sh[threadIdx.x] += t;
            __syncthreads();
        }
        int total = sh[255];
        if (idx < nw) w[idx] = run + sh[threadIdx.x] - v;
        __syncthreads();
        if (threadIdx.x == 0) run += total;
        __syncthreads();
    }
    if (total_out != nullptr && threadIdx.x == 0) *total_out = run;
}

__global__ void scan_finalize(int* off, const int* __restrict__ count,
                              const int* __restrict__ wsum, int n) {
    int idx = blockIdx.x * blockDim.x + threadIdx.x;
    if (idx < n) off[idx] = off[idx] - count[idx] + wsum[idx >> 6];
}

// ---------------- bucket-sorted compaction ----------------
__global__ void hist_keys(const unsigned long long* __restrict__ hk, int* hist, int T) {
    int s = blockIdx.x * blockDim.x + threadIdx.x;
    if (s >= T) return;
    unsigned long long k = hk[s];
    if (k != EMPTY_KEY) atomicAdd(&hist[key_code(k)], 1);
}

__global__ void assign_ids(const unsigned long long* __restrict__ hk, int* hid,
                           const int* __restrict__ histOff, int* histFill,
                           unsigned long long* uk, int T) {
    int s = blockIdx.x * blockDim.x + threadIdx.x;
    if (s >= T) return;
    unsigned long long k = hk[s];
    if (k == EMPTY_KEY) return;
    int code = key_code(k);
    int id = histOff[code] + atomicAdd(&histFill[code], 1);
    hid[s] = id;
    uk[id] = k;
}

__global__ void os_count_fused(int* os, const int* __restrict__ hid, int* count, int R) {
    int i = blockIdx.x * blockDim.x + threadIdx.x;
    if (i >= R) return;
    int id = hid[os[i]];
    os[i] = id;
    atomicAdd(&count[id], 1);
}

template<int D>
__global__ void build_neighbors(const unsigned long long* __restrict__ uk,
                                const unsigned long long* __restrict__ hk,
                                const int* __restrict__ hid,
                                int tmask, const int* cnt, int stride,
                                int* n1, int* n2) {
    int m = blockIdx.x * blockDim.x + threadIdx.x;
    if (m >= *cnt) return;
    unsigned long long k = uk[m];
    int c[D];
    #pragma unroll
    for (int i = 0; i < D; i++) c[i] = (int)((k >> (12 * i)) & 0xFFFULL) - 2048;
    for (int j = 0; j <= D; j++) {
        unsigned long long p1 = 0, p2 = 0;
        #pragma unroll
        for (int i = 0; i < D; i++) {
            int a = c[i] + ((i == j) ? D : -1);   // key - 1 + (D+1)*e_j
            int b = c[i] + ((i == j) ? -D : 1);   // key + 1 - (D+1)*e_j
            p1 |= ((unsigned long long)((unsigned)(a + 2048) & 0xFFFu)) << (12 * i);
            p2 |= ((unsigned long long)((unsigned)(b + 2048) & 0xFFFu)) << (12 * i);
        }
        n1[j * stride + m] = hash_lookup(hk, hid, tmask, p1);
        n2[j * stride + m] = hash_lookup(hk, hid, tmask, p2);
    }
}

template<int D1>
__global__ void fill_entries(const int* __restrict__ os, const float* __restrict__ wsv,
                             const int* __restrict__ off, int* fill, int2* epw, int R) {
    int idx = blockIdx.x * blockDim.x + threadIdx.x;
    if (idx >= R) return;
    int m = os[idx];
    int pos = off[m] + atomicAdd(&fill[m], 1);
    epw[pos] = make_int2(idx / D1, __float_as_int(wsv[idx]));
}

// ---------------- filter kernels (float4, padded C=24) ----------------
__global__ void gather_splat4(const float4* __restrict__ Qp, const int* __restrict__ off,
                              const int* __restrict__ count, const int2* __restrict__ epw,
                              float4* __restrict__ buf, const int* cnt) {
    int M = *cnt;
    int total = (M + 1) * CP4;
    int stride = gridDim.x * blockDim.x;
    for (int idx = blockIdx.x * blockDim.x + threadIdx.x; idx < total; idx += stride) {
        int row = idx / CP4, c4 = idx - row * CP4;
        float4 acc = make_float4(0.f, 0.f, 0.f, 0.f);
        if (row > 0) {
            int m = row - 1;
            int s = off[m], e = s + count[m];
            for (int t = s; t < e; t++) {
                int2 pw = epw[t];
                float w = __int_as_float(pw.y);
                float4 v = Qp[(size_t)pw.x * CP4 + c4];
                acc.x += w * v.x; acc.y += w * v.y; acc.z += w * v.z; acc.w += w * v.w;
            }
        }
        buf[idx] = acc;
    }
}

__global__ void gather_splat1(const int* __restrict__ off, const int* __restrict__ count,
                              const int2* __restrict__ epw, float* __restrict__ buf,
                              const int* cnt) {
    int M = *cnt;
    int stride = gridDim.x * blockDim.x;
    for (int row = blockIdx.x * blockDim.x + threadIdx.x; row <= M; row += stride) {
        if (row == 0) { buf[0] = 0.f; continue; }
        int m = row - 1;
        int s = off[m], e = s + count[m];
        float acc = 0.f;
        for (int t = s; t < e; t++) acc += __int_as_float(epw[t].y);
        buf[row] = acc;
    }
}

__global__ void blur4(const float4* __restrict__ in, float4* __restrict__ out,
                      const int* __restrict__ n1, const int* __restrict__ n2,
                      const int* cnt) {
    int M = *cnt;
    int total = (M + 1) * CP4;
    int stride = gridDim.x * blockDim.x;
    for (int idx = blockIdx.x * blockDim.x + threadIdx.x; idx < total; idx += stride) {
        int row = idx / CP4, c4 = idx - row * CP4;
        if (row == 0) { out[idx] = make_float4(0.f, 0.f, 0.f, 0.f); continue; }
        int m = row - 1;
        float4 a = in[(size_t)(n1[m] + 1) * CP4 + c4];
        float4 b = in[(size_t)(n2[m] + 1) * CP4 + c4];
        float4 x = in[idx];
        x.x += 0.5f * (a.x + b.x); x.y += 0.5f * (a.y + b.y);
        x.z += 0.5f * (a.z + b.z); x.w += 0.5f * (a.w + b.w);
        out[idx] = x;
    }
}

__global__ void blur1(const float* __restrict__ in, float* __restrict__ out,
                      const int* __restrict__ n1, const int* __restrict__ n2,
                      const int* cnt) {
    int M = *cnt;
    int stride = gridDim.x * blockDim.x;
    for (int row = blockIdx.x * blockDim.x + threadIdx.x; row <= M; row += stride) {
        if (row == 0) { out[0] = 0.f; continue; }
        int m = row - 1;
        out[row] = in[row] + 0.5f * (in[n1[m] + 1] + in[n2[m] + 1]);
    }
}

// fused slice(bilateral)+slice(spatial)+normalize -> one padded msg array
__global__ void slice_msg(const float4* __restrict__ bufb, const int* __restrict__ osb,
                          const float* __restrict__ wsb,
                          const float4* __restrict__ bufs, const int* __restrict__ oss,
                          const float* __restrict__ wss,
                          const float* __restrict__ nbv, const float* __restrict__ nsv,
                          float4* __restrict__ msgp, float alphaB, float alphaS) {
    int idx = blockIdx.x * blockDim.x + threadIdx.x;
    if (idx >= NPIX * CP4) return;
    int i = idx / CP4, c4 = idx - i * CP4;
    float4 sb = make_float4(0.f, 0.f, 0.f, 0.f);
    #pragma unroll
    for (int r = 0; r < DB1; r++) {
        float w = wsb[i * DB1 + r];
        float4 v = bufb[(size_t)(osb[i * DB1 + r] + 1) * CP4 + c4];
        sb.x += w * v.x; sb.y += w * v.y; sb.z += w * v.z; sb.w += w * v.w;
    }
    float4 ss = make_float4(0.f, 0.f, 0.f, 0.f);
    #pragma unroll
    for (int r = 0; r < DS1; r++) {
        float w = wss[i * DS1 + r];
        float4 v = bufs[(size_t)(oss[i * DS1 + r] + 1) * CP4 + c4];
        ss.x += w * v.x; ss.y += w * v.y; ss.z += w * v.z; ss.w += w * v.w;
    }
    float ib = 10.0f * alphaB / nbv[i];
    float is = 3.0f * alphaS / nsv[i];
    float4 msg;
    msg.x = ib * sb.x + is * ss.x;
    msg.y = ib * sb.y + is * ss.y;
    msg.z = ib * sb.z + is * ss.z;
    msg.w = ib * sb.w + is * ss.w;
    msgp[idx] = msg;
}

template<int D1>
__global__ void slice_norm(const float* __restrict__ buf, const int* __restrict__ os,
                           const float* __restrict__ wsv, float* normv, float alpha) {
    int i = blockIdx.x * blockDim.x + threadIdx.x;
    if (i >= NPIX) return;
    float s = 0.f;
    #pragma unroll
    for (int r = 0; r < D1; r++)
        s += wsv[i * D1 + r] * buf[os[i * D1 + r] + 1];
    normv[i] = alpha * s + 1e-20f;
}

// Q (d_out, 21/pixel) + Qp (padded 24/pixel, zero tail) written together
__global__ void update_q(const float* __restrict__ U, const float4* __restrict__ msgp,
                         float* __restrict__ Q, float4* __restrict__ Qp, int use_msg) {
    int i = blockIdx.x * blockDim.x + threadIdx.x;
    if (i >= NPIX) return;
    float msg[24];
    if (use_msg) {
        #pragma unroll
        for (int t = 0; t < CP4; t++) {
            float4 a = msgp[i * CP4 + t];
            msg[4 * t + 0] = a.x; msg[4 * t + 1] = a.y;
            msg[4 * t + 2] = a.z; msg[4 * t + 3] = a.w;
        }
    } else {
        #pragma unroll
        for (int t = 0; t < 24; t++) msg[t] = 0.f;
    }
    float l[NC];
    float mx = -1e30f;
    #pragma unroll
    for (int c = 0; c < NC; c++) {
        float v = -U[i * NC + c] + msg[c];
        l[c] = v; mx = fmaxf(mx, v);
    }
    float s = 0.f;
    #pragma unroll
    for (int c = 0; c < NC; c++) { float e = expf(l[c] - mx); l[c] = e; s += e; }
    float inv = 1.0f / s;
    float q[24];
    #pragma unroll
    for (int c = 0; c < NC; c++) {
        q[c] = l[c] * inv;
        Q[i * NC + c] = q[c];
    }
    q[21] = 0.f; q[22] = 0.f; q[23] = 0.f;
    #pragma unroll
    for (int t = 0; t < CP4; t++)
        Qp[i * CP4 + t] = make_float4(q[4 * t], q[4 * t + 1], q[4 * t + 2], q[4 * t + 3]);
}

// ---------------- host orchestration ----------------
extern "C" void kernel_launch(void* const* d_in, const int* in_sizes, int n_in,
                              void* d_out, int out_size, void* d_ws, size_t ws_size,
                              hipStream_t stream) {
    const float* U     = (const float*)d_in[0];
    const float* image = (const float*)d_in[1];
    float* Q = (float*)d_out;

    char* base = (char*)d_ws;
    size_t off = 0;
    auto alloc = [&](size_t bytes) -> void* {
        off = (off + 255) & ~(size_t)255;
        void* p = base + off; off += bytes; return p;
    };
    int*   os_b = (int*)  alloc((size_t)RB * 4);
    float* ws_b = (float*)alloc((size_t)RB * 4);
    int*   n1_b = (int*)  alloc((size_t)DB1 * RB * 4);
    int*   n2_b = (int*)  alloc((size_t)DB1 * RB * 4);
    unsigned long long* uk_b = (unsigned long long*)alloc((size_t)RB * 8);
    int*   os_s = (int*)  alloc((size_t)RS * 4);
    float* ws_s = (float*)alloc((size_t)RS * 4);
    int*   n1_s = (int*)  alloc((size_t)DS1 * RS * 4);
    int*   n2_s = (int*)  alloc((size_t)DS1 * RS * 4);
    unsigned long long* uk_s = (unsigned long long*)alloc((size_t)RS * 8);
    unsigned long long* hk = (unsigned long long*)alloc((size_t)TBS * 8);
    int*   hid  = (int*)  alloc((size_t)TBS * 4);
    int*   cnt  = (int*)  alloc(256);   // [0]=M_b, [1]=M_s
    int*   hist     = (int*)alloc((size_t)NBUCK * 4);
    int*   histOff  = (int*)alloc((size_t)NBUCK * 4);
    int*   histFill = (int*)alloc((size_t)NBUCK * 4);
    int*   wsums    = (int*)alloc((size_t)(RB / 64) * 4);
    int*   cntr_b = (int*)  alloc((size_t)RB * 4);
    int*   off_b  = (int*)  alloc((size_t)RB * 4);
    int*   fill_b = (int*)  alloc((size_t)RB * 4);
    int2*  epw_b  = (int2*) alloc((size_t)RB * 8);
    int*   cntr_s = (int*)  alloc((size_t)RS * 4);
    int*   off_s  = (int*)  alloc((size_t)RS * 4);
    int*   fill_s = (int*)  alloc((size_t)RS * 4);
    int2*  epw_s  = (int2*) alloc((size_t)RS * 8);
    float* norm_b = (float*)alloc((size_t)NPIX * 4);
    float* norm_s = (float*)alloc((size_t)NPIX * 4);
    float4* Qp   = (float4*)alloc((size_t)NPIX * CP4 * 16);
    float4* msgp = (float4*)alloc((size_t)NPIX * CP4 * 16);
    float4* buf0 = (float4*)alloc((size_t)(RB + 1) * CP4 * 16);
    float4* buf1 = (float4*)alloc((size_t)(RB + 1) * CP4 * 16);
    if (off > ws_size) return;

    const float ALPHA_B = (float)(1.0 / (1.0 + exp2(-(double)DB)));  // 32/33
    const float ALPHA_S = (float)(1.0 / (1.0 + exp2(-(double)DS)));  // 4/5

    constexpr int PG = 4096;    // bilateral-chain grid
    constexpr int PGS = 1024;   // spatial-chain grid (M_s is small)

    hipMemsetAsync(cnt, 0, 16, stream);

    // ---- build bilateral lattice ----
    hipMemsetAsync(hk, 0xFF, (size_t)TBS * 8, stream);
    hipMemsetAsync(cntr_b, 0, (size_t)RB * 4, stream);
    hipMemsetAsync(fill_b, 0, (size_t)RB * 4, stream);
    hipMemsetAsync(hist, 0, (size_t)NBUCK * 4, stream);
    hipMemsetAsync(histFill, 0, (size_t)NBUCK * 4, stream);
    build_bilateral<<<(NPIX + 255) / 256, 256, 0, stream>>>(image, hk, TBS - 1, os_b, ws_b);
    hist_keys<<<TBS / 256, 256, 0, stream>>>(hk, hist, TBS);
    scan_wave_partial<<<NBUCK / 256, 256, 0, stream>>>(hist, histOff, wsums, NBUCK);
    scan_partials_excl<<<1, 256, 0, stream>>>(wsums, NBUCK / 64, cnt + 0);
    scan_finalize<<<NBUCK / 256, 256, 0, stream>>>(histOff, hist, wsums, NBUCK);
    assign_ids<<<TBS / 256, 256, 0, stream>>>(hk, hid, histOff, histFill, uk_b, TBS);
    os_count_fused<<<(RB + 255) / 256, 256, 0, stream>>>(os_b, hid, cntr_b, RB);
    build_neighbors<DB><<<(RB + 255) / 256, 256, 0, stream>>>(uk_b, hk, hid, TBS - 1, cnt + 0, RB, n1_b, n2_b);
    scan_wave_partial<<<RB / 256, 256, 0, stream>>>(cntr_b, off_b, wsums, RB);
    scan_partials_excl<<<1, 256, 0, stream>>>(wsums, RB / 64, nullptr);
    scan_finalize<<<RB / 256, 256, 0, stream>>>(off_b, cntr_b, wsums, RB);
    fill_entries<DB1><<<(RB + 255) / 256, 256, 0, stream>>>(os_b, ws_b, off_b, fill_b, epw_b, RB);

    // ---- build spatial lattice (reuse hash region, smaller table) ----
    hipMemsetAsync(hk, 0xFF, (size_t)TSS * 8, stream);
    hipMemsetAsync(cntr_s, 0, (size_t)RS * 4, stream);
    hipMemsetAsync(fill_s, 0, (size_t)RS * 4, stream);
    hipMemsetAsync(hist, 0, (size_t)NBUCK * 4, stream);
    hipMemsetAsync(histFill, 0, (size_t)NBUCK * 4, stream);
    build_spatial<<<(NPIX + 255) / 256, 256, 0, stream>>>(hk, TSS - 1, os_s, ws_s);
    hist_keys<<<TSS / 256, 256, 0, stream>>>(hk, hist, TSS);
    scan_wave_partial<<<NBUCK / 256, 256, 0, stream>>>(hist, histOff, wsums, NBUCK);
    scan_partials_excl<<<1, 256, 0, stream>>>(wsums, NBUCK / 64, cnt + 1);
    scan_finalize<<<NBUCK / 256, 256, 0, stream>>>(histOff, hist, wsums, NBUCK);
    assign_ids<<<TSS / 256, 256, 0, stream>>>(hk, hid, histOff, histFill, uk_s, TSS);
    os_count_fused<<<(RS + 255) / 256, 256, 0, stream>>>(os_s, hid, cntr_s, RS);
    build_neighbors<DS><<<(RS + 255) / 256, 256, 0, stream>>>(uk_s, hk, hid, TSS - 1, cnt + 1, RS, n1_s, n2_s);
    scan_wave_partial<<<RS / 256, 256, 0, stream>>>(cntr_s, off_s, wsums, RS);
    scan_partials_excl<<<1, 256, 0, stream>>>(wsums, RS / 64, nullptr);
    scan_finalize<<<RS / 256, 256, 0, stream>>>(off_s, cntr_s, wsums, RS);
    fill_entries<DS1><<<(RS + 255) / 256, 256, 0, stream>>>(os_s, ws_s, off_s, fill_s, epw_s, RS);

    // ---- norm filters (C=1), computed once ----
    {
        float* nb0 = (float*)buf0; float* nb1 = (float*)buf1;
        gather_splat1<<<1024, 256, 0, stream>>>(off_b, cntr_b, epw_b, nb0, cnt + 0);
        float* a = nb0; float* b = nb1;
        for (int j = 0; j < DB1; j++) {
            blur1<<<1024, 256, 0, stream>>>(a, b, n1_b + (size_t)j * RB, n2_b + (size_t)j * RB, cnt + 0);
            float* t = a; a = b; b = t;
        }
        slice_norm<DB1><<<(NPIX + 255) / 256, 256, 0, stream>>>(a, os_b, ws_b, norm_b, ALPHA_B);

        gather_splat1<<<PGS, 256, 0, stream>>>(off_s, cntr_s, epw_s, nb0, cnt + 1);
        a = nb0; b = nb1;
        for (int j = 0; j < DS1; j++) {
            blur1<<<PGS, 256, 0, stream>>>(a, b, n1_s + (size_t)j * RS, n2_s + (size_t)j * RS, cnt + 1);
            float* t = a; a = b; b = t;
        }
        slice_norm<DS1><<<(NPIX + 255) / 256, 256, 0, stream>>>(a, os_s, ws_s, norm_s, ALPHA_S);
    }

    // ---- Q0 = softmax(-U) ----
    update_q<<<(NPIX + 255) / 256, 256, 0, stream>>>(U, msgp, Q, Qp, 0);

    // ---- 5 mean-field iterations ----
    for (int it = 0; it < 5; it++) {
        // bilateral: gather into buf0; 6 blurs buf0->buf1->...->buf0 (result buf0)
        gather_splat4<<<PG, 256, 0, stream>>>(Qp, off_b, cntr_b, epw_b, buf0, cnt + 0);
        float4* a = buf0; float4* b = buf1;
        for (int j = 0; j < DB1; j++) {
            blur4<<<PG, 256, 0, stream>>>(a, b, n1_b + (size_t)j * RB, n2_b + (size_t)j * RB, cnt + 0);
            float4* t = a; a = b; b = t;
        }
        float4* resB = a;   // buf0 after 6 swaps

        // spatial: gather into msgp; 3 blurs msgp->buf1->msgp->buf1 (result buf1).
        // buf1 only held the j=4 bilateral intermediate — free to reuse.
        gather_splat4<<<PGS, 256, 0, stream>>>(Qp, off_s, cntr_s, epw_s, msgp, cnt + 1);
        float4* c = msgp; float4* d = buf1;
        for (int j = 0; j < DS1; j++) {
            blur4<<<PGS, 256, 0, stream>>>(c, d, n1_s + (size_t)j * RS, n2_s + (size_t)j * RS, cnt + 1);
            float4* t = c; c = d; d = t;
        }
        float4* resS = c;   // buf1 after 3 swaps — no aliasing with msgp below

        // fused slices + normalization -> msgp (writes all NPIX*CP4)
        slice_msg<<<(NPIX * CP4 + 255) / 256, 256, 0, stream>>>(
            resB, os_b, ws_b, resS, os_s, ws_s, norm_b, norm_s, msgp, ALPHA_B, ALPHA_S);

        // Q = softmax(-U + msg)
        update_q<<<(NPIX + 255) / 256, 256, 0, stream>>>(U, msgp, Q, Qp, 1);
    }
}

// Round 9
// 1141.564 us; speedup vs baseline: 1.1559x; 1.1142x over previous
//
#include <hip/hip_runtime.h>
#include <hip/hip_fp16.h>
#include <cmath>

// ---------------- problem constants ----------------
constexpr int IMH = 320, IMW = 320, NPIX = IMH * IMW, NC = 21;
constexpr int CP4 = 6;           // padded channels / 4  (24 values per row)
constexpr int DB = 5, DB1 = 6;   // bilateral lattice dim
constexpr int DS = 2, DS1 = 3;   // spatial lattice dim
constexpr int RB = NPIX * DB1;   // splat entries (bilateral) = 614400
constexpr int RS = NPIX * DS1;   // (spatial) = 307200
constexpr int TBS = 1 << 20;     // hash table slots (bilateral)
constexpr int TSS = 1 << 18;     // hash table slots (spatial)
constexpr int NBUCK = 1 << 16;   // spatial-sort buckets (c0,c1 low bytes)

#define EMPTY_KEY 0xFFFFFFFFFFFFFFFFULL

__device__ __forceinline__ unsigned long long mix64(unsigned long long x) {
    x ^= x >> 33; x *= 0xff51afd7ed558ccdULL;
    x ^= x >> 33; x *= 0xc4ceb9fe1a85ec53ULL;
    x ^= x >> 33; return x;
}

// fp16 pack helpers: uint2 = 4 halves; math in fp32, storage fp16.
__device__ __forceinline__ float4 u2f(uint2 u) {
    __half2 a = *reinterpret_cast<__half2*>(&u.x);
    __half2 b = *reinterpret_cast<__half2*>(&u.y);
    float2 fa = __half22float2(a), fb = __half22float2(b);
    return make_float4(fa.x, fa.y, fb.x, fb.y);
}
__device__ __forceinline__ uint2 f2u(float4 v) {
    __half2 a = __floats2half2_rn(v.x, v.y);
    __half2 b = __floats2half2_rn(v.z, v.w);
    uint2 u;
    u.x = *reinterpret_cast<unsigned*>(&a);
    u.y = *reinterpret_cast<unsigned*>(&b);
    return u;
}

// NOTE: XCD block swizzle tried in r6/r7 REGRESSED (occupancy collapse on
// small-work grids). Plain blockIdx order. fp16 buffers introduced in r9:
// blur chain is streaming-bytes-bound, fp16 halves the bytes.

// ---------------- permutohedral embedding (matches reference op-for-op, f32) ----------------
template<int D>
__device__ void perm_embed(const float* f, float* bary, unsigned long long* pk) {
    constexpr int D1 = D + 1;
    float cf[D];
    #pragma unroll
    for (int i = 0; i < D; i++) {
        double s = sqrt(2.0 / 3.0) * (double)D1 / sqrt((double)((i + 1) * (i + 2)));
        cf[i] = f[i] * (float)s;
    }
    float csum[D];
    float acc = 0.f;
    #pragma unroll
    for (int i = D - 1; i >= 0; i--) { acc += cf[i]; csum[i] = acc; }
    float el[D1];
    el[0] = csum[0];
    #pragma unroll
    for (int i = 1; i < D; i++) el[i] = csum[i] - (float)i * cf[i - 1];
    el[D] = -(float)D * cf[D - 1];
    const float down = 1.0f / (float)D1;
    float rem0[D1]; int rank[D1]; int ssum = 0;
    #pragma unroll
    for (int i = 0; i < D1; i++) {
        float rd = rintf(el[i] * down);
        rem0[i] = rd * (float)D1;
        ssum += (int)rd;
    }
    float diff[D1];
    #pragma unroll
    for (int i = 0; i < D1; i++) diff[i] = el[i] - rem0[i];
    #pragma unroll
    for (int i = 0; i < D1; i++) {
        int r = 0;
        #pragma unroll
        for (int j = 0; j < D1; j++)
            r += (diff[j] > diff[i]) || ((diff[j] == diff[i]) && (j < i));
        rank[i] = r + ssum;
    }
    #pragma unroll
    for (int i = 0; i < D1; i++) {
        if (rank[i] < 0)      { rank[i] += D1; rem0[i] += (float)D1; }
        else if (rank[i] > D) { rank[i] -= D1; rem0[i] -= (float)D1; }
    }
    float b[D + 2];
    #pragma unroll
    for (int i = 0; i < D + 2; i++) b[i] = 0.f;
    #pragma unroll
    for (int i = 0; i < D1; i++) b[D - rank[i]]     += (el[i] - rem0[i]) * down;
    #pragma unroll
    for (int i = 0; i < D1; i++) b[D + 1 - rank[i]] -= (el[i] - rem0[i]) * down;
    b[0] += 1.0f + b[D + 1];
    #pragma unroll
    for (int i = 0; i < D1; i++) bary[i] = b[i];
    int key0[D];
    #pragma unroll
    for (int i = 0; i < D; i++) key0[i] = (int)rintf(rem0[i]);
    #pragma unroll
    for (int r = 0; r < D1; r++) {
        unsigned long long p = 0;
        #pragma unroll
        for (int i = 0; i < D; i++) {
            int c = key0[i] + ((rank[i] < D1 - r) ? r : r - D1);
            p |= ((unsigned long long)((unsigned)(c + 2048) & 0xFFFu)) << (12 * i);
        }
        pk[r] = p;
    }
}

// ---------------- hash table ----------------
__device__ __forceinline__ int hash_insert(unsigned long long* hk, int tmask, unsigned long long k) {
    int slot = (int)(mix64(k) & (unsigned long long)tmask);
    while (true) {
        unsigned long long prev = atomicCAS(&hk[slot], EMPTY_KEY, k);
        if (prev == EMPTY_KEY || prev == k) return slot;
        slot = (slot + 1) & tmask;
    }
}
__device__ __forceinline__ int hash_lookup(const unsigned long long* hk, const int* hid,
                                           int tmask, unsigned long long k) {
    int slot = (int)(mix64(k) & (unsigned long long)tmask);
    while (true) {
        unsigned long long v = hk[slot];
        if (v == k) return hid[slot];
        if (v == EMPTY_KEY) return -1;
        slot = (slot + 1) & tmask;
    }
}

// bucket code from low bytes of first two (biased) lattice coords
__device__ __forceinline__ int key_code(unsigned long long k) {
    int c0 = (int)(k & 0xFFFULL);
    int c1 = (int)((k >> 12) & 0xFFFULL);
    return ((c0 & 0xFF) << 8) | (c1 & 0xFF);
}

// ---------------- build kernels ----------------
__global__ void build_bilateral(const float* __restrict__ image, unsigned long long* hk,
                                int tmask, int* os, float* wsv) {
    int i = blockIdx.x * blockDim.x + threadIdx.x;
    if (i >= NPIX) return;
    int x = i % IMW, y = i / IMW;
    float f[DB];
    f[0] = (float)x / 80.0f;           // THETA_ALPHA
    f[1] = (float)y / 80.0f;
    f[2] = image[i * 3 + 0] / 13.0f;   // THETA_BETA
    f[3] = image[i * 3 + 1] / 13.0f;
    f[4] = image[i * 3 + 2] / 13.0f;
    float bary[DB1]; unsigned long long pk[DB1];
    perm_embed<DB>(f, bary, pk);
    #pragma unroll
    for (int r = 0; r < DB1; r++) {
        wsv[i * DB1 + r] = bary[r];
        os[i * DB1 + r] = hash_insert(hk, tmask, pk[r]);  // slot; remapped to id later
    }
}

__global__ void build_spatial(unsigned long long* hk, int tmask, int* os, float* wsv) {
    int i = blockIdx.x * blockDim.x + threadIdx.x;
    if (i >= NPIX) return;
    int x = i % IMW, y = i / IMW;
    float f[DS];
    f[0] = (float)x / 3.0f;            // THETA_GAMMA
    f[1] = (float)y / 3.0f;
    float bary[DS1]; unsigned long long pk[DS1];
    perm_embed<DS>(f, bary, pk);
    #pragma unroll
    for (int r = 0; r < DS1; r++) {
        wsv[i * DS1 + r] = bary[r];
        os[i * DS1 + r] = hash_insert(hk, tmask, pk[r]);
    }
}

// ---------------- barrier-free scan machinery ----------------
__global__ void scan_wave_partial(const int* __restrict__ count, int* incl, int* wsum, int n) {
    int idx = blockIdx.x * blockDim.x + threadIdx.x;
    int lane = threadIdx.x & 63;
    int v = (idx < n) ? count[idx] : 0;
    int s = v;
    #pragma unroll
    for (int d = 1; d < 64; d <<= 1) {
        int t = __shfl_up(s, d);
        if (lane >= d) s += t;
    }
    if (idx < n) incl[idx] = s;
    if (lane == 63) wsum[idx >> 6] = s;
}

__global__ void scan_partials_excl(int* w, int nw, int* total_out) {
    __shared__ int sh[256];
    __shared__ int run;
    if (threadIdx.x == 0) run = 0;
    __syncthreads();
    for (int basei = 0; basei < nw; basei += 256) {
        int idx = basei + threadIdx.x;
        int v = (idx < nw) ? w[idx] : 0;
        sh[threadIdx.x] = v;
        __syncthreads();
        for (int d = 1; d < 256; d <<= 1) {
            int t = (threadIdx.x >= d) ? sh[threadIdx.x - d] : 0;
            __syncthreads();
            sh[threadIdx.x] += t;
            __syncthreads();
        }
        int total = sh[255];
        if (idx < nw) w[idx] = run + sh[threadIdx.x] - v;
        __syncthreads();
        if (threadIdx.x == 0) run += total;
        __syncthreads();
    }
    if (total_out != nullptr && threadIdx.x == 0) *total_out = run;
}

__global__ void scan_finalize(int* off, const int* __restrict__ count,
                              const int* __restrict__ wsum, int n) {
    int idx = blockIdx.x * blockDim.x + threadIdx.x;
    if (idx < n) off[idx] = off[idx] - count[idx] + wsum[idx >> 6];
}

// ---------------- bucket-sorted compaction ----------------
__global__ void hist_keys(const unsigned long long* __restrict__ hk, int* hist, int T) {
    int s = blockIdx.x * blockDim.x + threadIdx.x;
    if (s >= T) return;
    unsigned long long k = hk[s];
    if (k != EMPTY_KEY) atomicAdd(&hist[key_code(k)], 1);
}

__global__ void assign_ids(const unsigned long long* __restrict__ hk, int* hid,
                           const int* __restrict__ histOff, int* histFill,
                           unsigned long long* uk, int T) {
    int s = blockIdx.x * blockDim.x + threadIdx.x;
    if (s >= T) return;
    unsigned long long k = hk[s];
    if (k == EMPTY_KEY) return;
    int code = key_code(k);
    int id = histOff[code] + atomicAdd(&histFill[code], 1);
    hid[s] = id;
    uk[id] = k;
}

__global__ void os_count_fused(int* os, const int* __restrict__ hid, int* count, int R) {
    int i = blockIdx.x * blockDim.x + threadIdx.x;
    if (i >= R) return;
    int id = hid[os[i]];
    os[i] = id;
    atomicAdd(&count[id], 1);
}

template<int D>
__global__ void build_neighbors(const unsigned long long* __restrict__ uk,
                                const unsigned long long* __restrict__ hk,
                                const int* __restrict__ hid,
                                int tmask, const int* cnt, int stride,
                                int* n1, int* n2) {
    int m = blockIdx.x * blockDim.x + threadIdx.x;
    if (m >= *cnt) return;
    unsigned long long k = uk[m];
    int c[D];
    #pragma unroll
    for (int i = 0; i < D; i++) c[i] = (int)((k >> (12 * i)) & 0xFFFULL) - 2048;
    for (int j = 0; j <= D; j++) {
        unsigned long long p1 = 0, p2 = 0;
        #pragma unroll
        for (int i = 0; i < D; i++) {
            int a = c[i] + ((i == j) ? D : -1);   // key - 1 + (D+1)*e_j
            int b = c[i] + ((i == j) ? -D : 1);   // key + 1 - (D+1)*e_j
            p1 |= ((unsigned long long)((unsigned)(a + 2048) & 0xFFFu)) << (12 * i);
            p2 |= ((unsigned long long)((unsigned)(b + 2048) & 0xFFFu)) << (12 * i);
        }
        n1[j * stride + m] = hash_lookup(hk, hid, tmask, p1);
        n2[j * stride + m] = hash_lookup(hk, hid, tmask, p2);
    }
}

template<int D1>
__global__ void fill_entries(const int* __restrict__ os, const float* __restrict__ wsv,
                             const int* __restrict__ off, int* fill, int2* epw, int R) {
    int idx = blockIdx.x * blockDim.x + threadIdx.x;
    if (idx >= R) return;
    int m = os[idx];
    int pos = off[m] + atomicAdd(&fill[m], 1);
    epw[pos] = make_int2(idx / D1, __float_as_int(wsv[idx]));
}

// ---------------- filter kernels (fp16 storage, fp32 math, padded C=24) ----------------
// buf rows: row 0 = zero sink; row m+1 = lattice point m; 6 uint2 (24 halves)/row.
__global__ void gather_splat_h(const uint2* __restrict__ Qh, const int* __restrict__ off,
                               const int* __restrict__ count, const int2* __restrict__ epw,
                               uint2* __restrict__ buf, const int* cnt) {
    int M = *cnt;
    int total = (M + 1) * CP4;
    int stride = gridDim.x * blockDim.x;
    for (int idx = blockIdx.x * blockDim.x + threadIdx.x; idx < total; idx += stride) {
        int row = idx / CP4, c4 = idx - row * CP4;
        float4 acc = make_float4(0.f, 0.f, 0.f, 0.f);
        if (row > 0) {
            int m = row - 1;
            int s = off[m], e = s + count[m];
            for (int t = s; t < e; t++) {
                int2 pw = epw[t];
                float w = __int_as_float(pw.y);
                float4 v = u2f(Qh[(size_t)pw.x * CP4 + c4]);
                acc.x += w * v.x; acc.y += w * v.y; acc.z += w * v.z; acc.w += w * v.w;
            }
        }
        buf[idx] = f2u(acc);
    }
}

__global__ void gather_splat1(const int* __restrict__ off, const int* __restrict__ count,
                              const int2* __restrict__ epw, float* __restrict__ buf,
                              const int* cnt) {
    int M = *cnt;
    int stride = gridDim.x * blockDim.x;
    for (int row = blockIdx.x * blockDim.x + threadIdx.x; row <= M; row += stride) {
        if (row == 0) { buf[0] = 0.f; continue; }
        int m = row - 1;
        int s = off[m], e = s + count[m];
        float acc = 0.f;
        for (int t = s; t < e; t++) acc += __int_as_float(epw[t].y);
        buf[row] = acc;
    }
}

__global__ void blur_h(const uint2* __restrict__ in, uint2* __restrict__ out,
                       const int* __restrict__ n1, const int* __restrict__ n2,
                       const int* cnt) {
    int M = *cnt;
    int total = (M + 1) * CP4;
    int stride = gridDim.x * blockDim.x;
    for (int idx = blockIdx.x * blockDim.x + threadIdx.x; idx < total; idx += stride) {
        int row = idx / CP4, c4 = idx - row * CP4;
        if (row == 0) { out[idx] = make_uint2(0u, 0u); continue; }  // fp16 zeros
        int m = row - 1;
        float4 a = u2f(in[(size_t)(n1[m] + 1) * CP4 + c4]);
        float4 b = u2f(in[(size_t)(n2[m] + 1) * CP4 + c4]);
        float4 x = u2f(in[idx]);
        x.x += 0.5f * (a.x + b.x); x.y += 0.5f * (a.y + b.y);
        x.z += 0.5f * (a.z + b.z); x.w += 0.5f * (a.w + b.w);
        out[idx] = f2u(x);
    }
}

__global__ void blur1(const float* __restrict__ in, float* __restrict__ out,
                      const int* __restrict__ n1, const int* __restrict__ n2,
                      const int* cnt) {
    int M = *cnt;
    int stride = gridDim.x * blockDim.x;
    for (int row = blockIdx.x * blockDim.x + threadIdx.x; row <= M; row += stride) {
        if (row == 0) { out[0] = 0.f; continue; }
        int m = row - 1;
        out[row] = in[row] + 0.5f * (in[n1[m] + 1] + in[n2[m] + 1]);
    }
}

// fused slice(bilateral)+slice(spatial)+normalize -> one padded fp32 msg array
__global__ void slice_msg(const uint2* __restrict__ bufb, const int* __restrict__ osb,
                          const float* __restrict__ wsb,
                          const uint2* __restrict__ bufs, const int* __restrict__ oss,
                          const float* __restrict__ wss,
                          const float* __restrict__ nbv, const float* __restrict__ nsv,
                          float4* __restrict__ msgp, float alphaB, float alphaS) {
    int idx = blockIdx.x * blockDim.x + threadIdx.x;
    if (idx >= NPIX * CP4) return;
    int i = idx / CP4, c4 = idx - i * CP4;
    float4 sb = make_float4(0.f, 0.f, 0.f, 0.f);
    #pragma unroll
    for (int r = 0; r < DB1; r++) {
        float w = wsb[i * DB1 + r];
        float4 v = u2f(bufb[(size_t)(osb[i * DB1 + r] + 1) * CP4 + c4]);
        sb.x += w * v.x; sb.y += w * v.y; sb.z += w * v.z; sb.w += w * v.w;
    }
    float4 ss = make_float4(0.f, 0.f, 0.f, 0.f);
    #pragma unroll
    for (int r = 0; r < DS1; r++) {
        float w = wss[i * DS1 + r];
        float4 v = u2f(bufs[(size_t)(oss[i * DS1 + r] + 1) * CP4 + c4]);
        ss.x += w * v.x; ss.y += w * v.y; ss.z += w * v.z; ss.w += w * v.w;
    }
    float ib = 10.0f * alphaB / nbv[i];
    float is = 3.0f * alphaS / nsv[i];
    float4 msg;
    msg.x = ib * sb.x + is * ss.x;
    msg.y = ib * sb.y + is * ss.y;
    msg.z = ib * sb.z + is * ss.z;
    msg.w = ib * sb.w + is * ss.w;
    msgp[idx] = msg;
}

template<int D1>
__global__ void slice_norm(const float* __restrict__ buf, const int* __restrict__ os,
                           const float* __restrict__ wsv, float* normv, float alpha) {
    int i = blockIdx.x * blockDim.x + threadIdx.x;
    if (i >= NPIX) return;
    float s = 0.f;
    #pragma unroll
    for (int r = 0; r < D1; r++)
        s += wsv[i * D1 + r] * buf[os[i * D1 + r] + 1];
    normv[i] = alpha * s + 1e-20f;
}

// Q (d_out, fp32 exact) + Qh (padded fp16, zero tail) written together
__global__ void update_q(const float* __restrict__ U, const float4* __restrict__ msgp,
                         float* __restrict__ Q, uint2* __restrict__ Qh, int use_msg) {
    int i = blockIdx.x * blockDim.x + threadIdx.x;
    if (i >= NPIX) return;
    float msg[24];
    if (use_msg) {
        #pragma unroll
        for (int t = 0; t < CP4; t++) {
            float4 a = msgp[i * CP4 + t];
            msg[4 * t + 0] = a.x; msg[4 * t + 1] = a.y;
            msg[4 * t + 2] = a.z; msg[4 * t + 3] = a.w;
        }
    } else {
        #pragma unroll
        for (int t = 0; t < 24; t++) msg[t] = 0.f;
    }
    float l[NC];
    float mx = -1e30f;
    #pragma unroll
    for (int c = 0; c < NC; c++) {
        float v = -U[i * NC + c] + msg[c];
        l[c] = v; mx = fmaxf(mx, v);
    }
    float s = 0.f;
    #pragma unroll
    for (int c = 0; c < NC; c++) { float e = expf(l[c] - mx); l[c] = e; s += e; }
    float inv = 1.0f / s;
    float q[24];
    #pragma unroll
    for (int c = 0; c < NC; c++) {
        q[c] = l[c] * inv;
        Q[i * NC + c] = q[c];
    }
    q[21] = 0.f; q[22] = 0.f; q[23] = 0.f;
    #pragma unroll
    for (int t = 0; t < CP4; t++)
        Qh[i * CP4 + t] = f2u(make_float4(q[4 * t], q[4 * t + 1], q[4 * t + 2], q[4 * t + 3]));
}

// ---------------- host orchestration ----------------
extern "C" void kernel_launch(void* const* d_in, const int* in_sizes, int n_in,
                              void* d_out, int out_size, void* d_ws, size_t ws_size,
                              hipStream_t stream) {
    const float* U     = (const float*)d_in[0];
    const float* image = (const float*)d_in[1];
    float* Q = (float*)d_out;

    char* base = (char*)d_ws;
    size_t off = 0;
    auto alloc = [&](size_t bytes) -> void* {
        off = (off + 255) & ~(size_t)255;
        void* p = base + off; off += bytes; return p;
    };
    int*   os_b = (int*)  alloc((size_t)RB * 4);
    float* ws_b = (float*)alloc((size_t)RB * 4);
    int*   n1_b = (int*)  alloc((size_t)DB1 * RB * 4);
    int*   n2_b = (int*)  alloc((size_t)DB1 * RB * 4);
    unsigned long long* uk_b = (unsigned long long*)alloc((size_t)RB * 8);
    int*   os_s = (int*)  alloc((size_t)RS * 4);
    float* ws_s = (float*)alloc((size_t)RS * 4);
    int*   n1_s = (int*)  alloc((size_t)DS1 * RS * 4);
    int*   n2_s = (int*)  alloc((size_t)DS1 * RS * 4);
    unsigned long long* uk_s = (unsigned long long*)alloc((size_t)RS * 8);
    unsigned long long* hk = (unsigned long long*)alloc((size_t)TBS * 8);
    int*   hid  = (int*)  alloc((size_t)TBS * 4);
    int*   cnt  = (int*)  alloc(256);   // [0]=M_b, [1]=M_s
    int*   hist     = (int*)alloc((size_t)NBUCK * 4);
    int*   histOff  = (int*)alloc((size_t)NBUCK * 4);
    int*   histFill = (int*)alloc((size_t)NBUCK * 4);
    int*   wsums    = (int*)alloc((size_t)(RB / 64) * 4);
    int*   cntr_b = (int*)  alloc((size_t)RB * 4);
    int*   off_b  = (int*)  alloc((size_t)RB * 4);
    int*   fill_b = (int*)  alloc((size_t)RB * 4);
    int2*  epw_b  = (int2*) alloc((size_t)RB * 8);
    int*   cntr_s = (int*)  alloc((size_t)RS * 4);
    int*   off_s  = (int*)  alloc((size_t)RS * 4);
    int*   fill_s = (int*)  alloc((size_t)RS * 4);
    int2*  epw_s  = (int2*) alloc((size_t)RS * 8);
    float* norm_b = (float*)alloc((size_t)NPIX * 4);
    float* norm_s = (float*)alloc((size_t)NPIX * 4);
    uint2* Qh   = (uint2*)alloc((size_t)NPIX * CP4 * 8);          // fp16 Q, 4.9 MB
    float4* msgp = (float4*)alloc((size_t)NPIX * CP4 * 16);       // fp32 msg
    uint2* buf0 = (uint2*)alloc((size_t)(RB + 1) * CP4 * 8);      // fp16 bilateral buf
    uint2* buf1 = (uint2*)alloc((size_t)(RB + 1) * CP4 * 8);
    uint2* sbuf0 = (uint2*)alloc((size_t)(RS + 1) * CP4 * 8);     // fp16 spatial buf
    uint2* sbuf1 = (uint2*)alloc((size_t)(RS + 1) * CP4 * 8);
    float* nbuf0 = (float*)alloc((size_t)(RB + 1) * 4);           // fp32 norm scratch
    float* nbuf1 = (float*)alloc((size_t)(RB + 1) * 4);
    if (off > ws_size) return;

    const float ALPHA_B = (float)(1.0 / (1.0 + exp2(-(double)DB)));  // 32/33
    const float ALPHA_S = (float)(1.0 / (1.0 + exp2(-(double)DS)));  // 4/5

    constexpr int PG = 4096;    // bilateral-chain grid (256-thread blocks)
    constexpr int PGS = 2048;   // spatial-chain grid (64-thread blocks: M_s small,
                                // spread long gather loops across more CUs)

    hipMemsetAsync(cnt, 0, 16, stream);

    // ---- build bilateral lattice ----
    hipMemsetAsync(hk, 0xFF, (size_t)TBS * 8, stream);
    hipMemsetAsync(cntr_b, 0, (size_t)RB * 4, stream);
    hipMemsetAsync(fill_b, 0, (size_t)RB * 4, stream);
    hipMemsetAsync(hist, 0, (size_t)NBUCK * 4, stream);
    hipMemsetAsync(histFill, 0, (size_t)NBUCK * 4, stream);
    build_bilateral<<<(NPIX + 255) / 256, 256, 0, stream>>>(image, hk, TBS - 1, os_b, ws_b);
    hist_keys<<<TBS / 256, 256, 0, stream>>>(hk, hist, TBS);
    scan_wave_partial<<<NBUCK / 256, 256, 0, stream>>>(hist, histOff, wsums, NBUCK);
    scan_partials_excl<<<1, 256, 0, stream>>>(wsums, NBUCK / 64, cnt + 0);
    scan_finalize<<<NBUCK / 256, 256, 0, stream>>>(histOff, hist, wsums, NBUCK);
    assign_ids<<<TBS / 256, 256, 0, stream>>>(hk, hid, histOff, histFill, uk_b, TBS);
    os_count_fused<<<(RB + 255) / 256, 256, 0, stream>>>(os_b, hid, cntr_b, RB);
    build_neighbors<DB><<<(RB + 255) / 256, 256, 0, stream>>>(uk_b, hk, hid, TBS - 1, cnt + 0, RB, n1_b, n2_b);
    scan_wave_partial<<<RB / 256, 256, 0, stream>>>(cntr_b, off_b, wsums, RB);
    scan_partials_excl<<<1, 256, 0, stream>>>(wsums, RB / 64, nullptr);
    scan_finalize<<<RB / 256, 256, 0, stream>>>(off_b, cntr_b, wsums, RB);
    fill_entries<DB1><<<(RB + 255) / 256, 256, 0, stream>>>(os_b, ws_b, off_b, fill_b, epw_b, RB);

    // ---- build spatial lattice (reuse hash region, smaller table) ----
    hipMemsetAsync(hk, 0xFF, (size_t)TSS * 8, stream);
    hipMemsetAsync(cntr_s, 0, (size_t)RS * 4, stream);
    hipMemsetAsync(fill_s, 0, (size_t)RS * 4, stream);
    hipMemsetAsync(hist, 0, (size_t)NBUCK * 4, stream);
    hipMemsetAsync(histFill, 0, (size_t)NBUCK * 4, stream);
    build_spatial<<<(NPIX + 255) / 256, 256, 0, stream>>>(hk, TSS - 1, os_s, ws_s);
    hist_keys<<<TSS / 256, 256, 0, stream>>>(hk, hist, TSS);
    scan_wave_partial<<<NBUCK / 256, 256, 0, stream>>>(hist, histOff, wsums, NBUCK);
    scan_partials_excl<<<1, 256, 0, stream>>>(wsums, NBUCK / 64, cnt + 1);
    scan_finalize<<<NBUCK / 256, 256, 0, stream>>>(histOff, hist, wsums, NBUCK);
    assign_ids<<<TSS / 256, 256, 0, stream>>>(hk, hid, histOff, histFill, uk_s, TSS);
    os_count_fused<<<(RS + 255) / 256, 256, 0, stream>>>(os_s, hid, cntr_s, RS);
    build_neighbors<DS><<<(RS + 255) / 256, 256, 0, stream>>>(uk_s, hk, hid, TSS - 1, cnt + 1, RS, n1_s, n2_s);
    scan_wave_partial<<<RS / 256, 256, 0, stream>>>(cntr_s, off_s, wsums, RS);
    scan_partials_excl<<<1, 256, 0, stream>>>(wsums, RS / 64, nullptr);
    scan_finalize<<<RS / 256, 256, 0, stream>>>(off_s, cntr_s, wsums, RS);
    fill_entries<DS1><<<(RS + 255) / 256, 256, 0, stream>>>(os_s, ws_s, off_s, fill_s, epw_s, RS);

    // ---- norm filters (C=1, fp32), computed once ----
    {
        gather_splat1<<<1024, 256, 0, stream>>>(off_b, cntr_b, epw_b, nbuf0, cnt + 0);
        float* a = nbuf0; float* b = nbuf1;
        for (int j = 0; j < DB1; j++) {
            blur1<<<1024, 256, 0, stream>>>(a, b, n1_b + (size_t)j * RB, n2_b + (size_t)j * RB, cnt + 0);
            float* t = a; a = b; b = t;
        }
        slice_norm<DB1><<<(NPIX + 255) / 256, 256, 0, stream>>>(a, os_b, ws_b, norm_b, ALPHA_B);

        gather_splat1<<<PGS, 64, 0, stream>>>(off_s, cntr_s, epw_s, nbuf0, cnt + 1);
        a = nbuf0; b = nbuf1;
        for (int j = 0; j < DS1; j++) {
            blur1<<<PGS, 64, 0, stream>>>(a, b, n1_s + (size_t)j * RS, n2_s + (size_t)j * RS, cnt + 1);
            float* t = a; a = b; b = t;
        }
        slice_norm<DS1><<<(NPIX + 255) / 256, 256, 0, stream>>>(a, os_s, ws_s, norm_s, ALPHA_S);
    }

    // ---- Q0 = softmax(-U) ----
    update_q<<<(NPIX + 255) / 256, 256, 0, stream>>>(U, msgp, Q, Qh, 0);

    // ---- 5 mean-field iterations ----
    for (int it = 0; it < 5; it++) {
        // bilateral: gather into buf0; 6 blurs buf0->buf1->...->buf0 (result buf0)
        gather_splat_h<<<PG, 256, 0, stream>>>(Qh, off_b, cntr_b, epw_b, buf0, cnt + 0);
        uint2* a = buf0; uint2* b = buf1;
        for (int j = 0; j < DB1; j++) {
            blur_h<<<PG, 256, 0, stream>>>(a, b, n1_b + (size_t)j * RB, n2_b + (size_t)j * RB, cnt + 0);
            uint2* t = a; a = b; b = t;
        }
        uint2* resB = a;   // buf0 after 6 swaps

        // spatial: gather into sbuf0; 3 blurs sbuf0->sbuf1->sbuf0->sbuf1 (result sbuf1)
        gather_splat_h<<<PGS, 64, 0, stream>>>(Qh, off_s, cntr_s, epw_s, sbuf0, cnt + 1);
        uint2* c = sbuf0; uint2* d = sbuf1;
        for (int j = 0; j < DS1; j++) {
            blur_h<<<PGS, 64, 0, stream>>>(c, d, n1_s + (size_t)j * RS, n2_s + (size_t)j * RS, cnt + 1);
            uint2* t = c; c = d; d = t;
        }
        uint2* resS = c;   // sbuf1 after 3 swaps

        // fused slices + normalization -> msgp (fp32)
        slice_msg<<<(NPIX * CP4 + 255) / 256, 256, 0, stream>>>(
            resB, os_b, ws_b, resS, os_s, ws_s, norm_b, norm_s, msgp, ALPHA_B, ALPHA_S);

        // Q = softmax(-U + msg)
        update_q<<<(NPIX + 255) / 256, 256, 0, stream>>>(U, msgp, Q, Qh, 1);
    }
}

// Round 10
// 1034.164 us; speedup vs baseline: 1.2759x; 1.1039x over previous
//
#include <hip/hip_runtime.h>
#include <hip/hip_fp16.h>
#include <cmath>

// ---------------- problem constants ----------------
constexpr int IMH = 320, IMW = 320, NPIX = IMH * IMW, NC = 21;
constexpr int CP4 = 6;           // padded channels / 4  (24 values per row)
constexpr int DB = 5, DB1 = 6;   // bilateral lattice dim
constexpr int DS = 2, DS1 = 3;   // spatial lattice dim
constexpr int RB = NPIX * DB1;   // splat entries (bilateral) = 614400
constexpr int RS = NPIX * DS1;   // (spatial) = 307200
constexpr int TBS = 1 << 20;     // hash table slots (bilateral)
constexpr int TSS = 1 << 18;     // hash table slots (spatial)
constexpr int NBUCK = 1 << 16;   // spatial-sort buckets (c0,c1 low bytes)

// Combined lattice-value buffer layout (static partition):
//   bilateral: row 0 = sink, point m -> row m+1           (rows [0, RB])
//   spatial:   row RB+1 = sink, point m -> row RB+2+m     (rows [RB+1, ...])
// spatial neighbor n=-1 maps to RB+2+(-1) = RB+1 = sink automatically.

#define EMPTY_KEY 0xFFFFFFFFFFFFFFFFULL

__device__ __forceinline__ unsigned long long mix64(unsigned long long x) {
    x ^= x >> 33; x *= 0xff51afd7ed558ccdULL;
    x ^= x >> 33; x *= 0xc4ceb9fe1a85ec53ULL;
    x ^= x >> 33; return x;
}

// fp16 pack helpers: uint2 = 4 halves; math in fp32, storage fp16.
__device__ __forceinline__ float4 u2f(uint2 u) {
    __half2 a = *reinterpret_cast<__half2*>(&u.x);
    __half2 b = *reinterpret_cast<__half2*>(&u.y);
    float2 fa = __half22float2(a), fb = __half22float2(b);
    return make_float4(fa.x, fa.y, fb.x, fb.y);
}
__device__ __forceinline__ uint2 f2u(float4 v) {
    __half2 a = __floats2half2_rn(v.x, v.y);
    __half2 b = __floats2half2_rn(v.z, v.w);
    uint2 u;
    u.x = *reinterpret_cast<unsigned*>(&a);
    u.y = *reinterpret_cast<unsigned*>(&b);
    return u;
}

// ---------------- permutohedral embedding (matches reference op-for-op, f32) ----------------
template<int D>
__device__ void perm_embed(const float* f, float* bary, unsigned long long* pk) {
    constexpr int D1 = D + 1;
    float cf[D];
    #pragma unroll
    for (int i = 0; i < D; i++) {
        double s = sqrt(2.0 / 3.0) * (double)D1 / sqrt((double)((i + 1) * (i + 2)));
        cf[i] = f[i] * (float)s;
    }
    float csum[D];
    float acc = 0.f;
    #pragma unroll
    for (int i = D - 1; i >= 0; i--) { acc += cf[i]; csum[i] = acc; }
    float el[D1];
    el[0] = csum[0];
    #pragma unroll
    for (int i = 1; i < D; i++) el[i] = csum[i] - (float)i * cf[i - 1];
    el[D] = -(float)D * cf[D - 1];
    const float down = 1.0f / (float)D1;
    float rem0[D1]; int rank[D1]; int ssum = 0;
    #pragma unroll
    for (int i = 0; i < D1; i++) {
        float rd = rintf(el[i] * down);
        rem0[i] = rd * (float)D1;
        ssum += (int)rd;
    }
    float diff[D1];
    #pragma unroll
    for (int i = 0; i < D1; i++) diff[i] = el[i] - rem0[i];
    #pragma unroll
    for (int i = 0; i < D1; i++) {
        int r = 0;
        #pragma unroll
        for (int j = 0; j < D1; j++)
            r += (diff[j] > diff[i]) || ((diff[j] == diff[i]) && (j < i));
        rank[i] = r + ssum;
    }
    #pragma unroll
    for (int i = 0; i < D1; i++) {
        if (rank[i] < 0)      { rank[i] += D1; rem0[i] += (float)D1; }
        else if (rank[i] > D) { rank[i] -= D1; rem0[i] -= (float)D1; }
    }
    float b[D + 2];
    #pragma unroll
    for (int i = 0; i < D + 2; i++) b[i] = 0.f;
    #pragma unroll
    for (int i = 0; i < D1; i++) b[D - rank[i]]     += (el[i] - rem0[i]) * down;
    #pragma unroll
    for (int i = 0; i < D1; i++) b[D + 1 - rank[i]] -= (el[i] - rem0[i]) * down;
    b[0] += 1.0f + b[D + 1];
    #pragma unroll
    for (int i = 0; i < D1; i++) bary[i] = b[i];
    int key0[D];
    #pragma unroll
    for (int i = 0; i < D; i++) key0[i] = (int)rintf(rem0[i]);
    #pragma unroll
    for (int r = 0; r < D1; r++) {
        unsigned long long p = 0;
        #pragma unroll
        for (int i = 0; i < D; i++) {
            int c = key0[i] + ((rank[i] < D1 - r) ? r : r - D1);
            p |= ((unsigned long long)((unsigned)(c + 2048) & 0xFFFu)) << (12 * i);
        }
        pk[r] = p;
    }
}

// ---------------- hash table ----------------
__device__ __forceinline__ int hash_insert(unsigned long long* hk, int tmask, unsigned long long k) {
    int slot = (int)(mix64(k) & (unsigned long long)tmask);
    while (true) {
        unsigned long long prev = atomicCAS(&hk[slot], EMPTY_KEY, k);
        if (prev == EMPTY_KEY || prev == k) return slot;
        slot = (slot + 1) & tmask;
    }
}
__device__ __forceinline__ int hash_lookup(const unsigned long long* hk, const int* hid,
                                           int tmask, unsigned long long k) {
    int slot = (int)(mix64(k) & (unsigned long long)tmask);
    while (true) {
        unsigned long long v = hk[slot];
        if (v == k) return hid[slot];
        if (v == EMPTY_KEY) return -1;
        slot = (slot + 1) & tmask;
    }
}

__device__ __forceinline__ int key_code(unsigned long long k) {
    int c0 = (int)(k & 0xFFFULL);
    int c1 = (int)((k >> 12) & 0xFFFULL);
    return ((c0 & 0xFF) << 8) | (c1 & 0xFF);
}

// ---------------- build kernels ----------------
// one launch builds both lattices (hk = unified table: [0,TBS) bilateral, [TBS,TBS+TSS) spatial)
__global__ void build_both(const float* __restrict__ image, unsigned long long* hk,
                           int* os, float* wsv) {
    int i = blockIdx.x * blockDim.x + threadIdx.x;
    if (i < NPIX) {
        int x = i % IMW, y = i / IMW;
        float f[DB];
        f[0] = (float)x / 80.0f;
        f[1] = (float)y / 80.0f;
        f[2] = image[i * 3 + 0] / 13.0f;
        f[3] = image[i * 3 + 1] / 13.0f;
        f[4] = image[i * 3 + 2] / 13.0f;
        float bary[DB1]; unsigned long long pk[DB1];
        perm_embed<DB>(f, bary, pk);
        #pragma unroll
        for (int r = 0; r < DB1; r++) {
            wsv[i * DB1 + r] = bary[r];
            os[i * DB1 + r] = hash_insert(hk, TBS - 1, pk[r]);   // local slot in table b
        }
    } else if (i < 2 * NPIX) {
        int ip = i - NPIX;
        int x = ip % IMW, y = ip / IMW;
        float f[DS];
        f[0] = (float)x / 3.0f;
        f[1] = (float)y / 3.0f;
        float bary[DS1]; unsigned long long pk[DS1];
        perm_embed<DS>(f, bary, pk);
        #pragma unroll
        for (int r = 0; r < DS1; r++) {
            wsv[RB + ip * DS1 + r] = bary[r];
            os[RB + ip * DS1 + r] = hash_insert(hk + TBS, TSS - 1, pk[r]);  // local slot
        }
    }
}

// ---------------- barrier-free scan machinery ----------------
__global__ void scan_wave_partial(const int* __restrict__ count, int* incl, int* wsum, int n) {
    int idx = blockIdx.x * blockDim.x + threadIdx.x;
    int lane = threadIdx.x & 63;
    int v = (idx < n) ? count[idx] : 0;
    int s = v;
    #pragma unroll
    for (int d = 1; d < 64; d <<= 1) {
        int t = __shfl_up(s, d);
        if (lane >= d) s += t;
    }
    if (idx < n) incl[idx] = s;
    if (lane == 63) wsum[idx >> 6] = s;
}

__global__ void scan_partials_excl(int* w, int nw, int* total_out) {
    __shared__ int sh[256];
    __shared__ int run;
    if (threadIdx.x == 0) run = 0;
    __syncthreads();
    for (int basei = 0; basei < nw; basei += 256) {
        int idx = basei + threadIdx.x;
        int v = (idx < nw) ? w[idx] : 0;
        sh[threadIdx.x] = v;
        __syncthreads();
        for (int d = 1; d < 256; d <<= 1) {
            int t = (threadIdx.x >= d) ? sh[threadIdx.x - d] : 0;
            __syncthreads();
            sh[threadIdx.x] += t;
            __syncthreads();
        }
        int total = sh[255];
        if (idx < nw) w[idx] = run + sh[threadIdx.x] - v;
        __syncthreads();
        if (threadIdx.x == 0) run += total;
        __syncthreads();
    }
    if (total_out != nullptr && threadIdx.x == 0) *total_out = run;
}

__global__ void scan_finalize(int* off, const int* __restrict__ count,
                              const int* __restrict__ wsum, int n) {
    int idx = blockIdx.x * blockDim.x + threadIdx.x;
    if (idx < n) off[idx] = off[idx] - count[idx] + wsum[idx >> 6];
}

// ---------------- bucket-sorted compaction ----------------
// hist over BOTH tables in one pass (hist halves: [0,NBUCK) b, [NBUCK,2N) s)
__global__ void hist_both(const unsigned long long* __restrict__ hk, int* hist) {
    int s = blockIdx.x * blockDim.x + threadIdx.x;
    if (s >= TBS + TSS) return;
    unsigned long long k = hk[s];
    if (k == EMPTY_KEY) return;
    int half = (s < TBS) ? 0 : NBUCK;
    atomicAdd(&hist[half + key_code(k)], 1);
}

__global__ void assign_both(const unsigned long long* __restrict__ hk, int* hid,
                            const int* __restrict__ histOff, int* histFill,
                            unsigned long long* uk_b, unsigned long long* uk_s) {
    int s = blockIdx.x * blockDim.x + threadIdx.x;
    if (s >= TBS + TSS) return;
    unsigned long long k = hk[s];
    if (k == EMPTY_KEY) return;
    int half = (s < TBS) ? 0 : NBUCK;
    int code = half + key_code(k);
    int id = histOff[code] + atomicAdd(&histFill[code], 1);
    hid[s] = id;
    if (s < TBS) uk_b[id] = k; else uk_s[id] = k;
}

// unified os remap + cntr histogram (cntr slots: [0,RB) bilateral ids, [RB,RB+RS) spatial)
__global__ void os_count_both(int* os, const int* __restrict__ hid, int* cntr) {
    int i = blockIdx.x * blockDim.x + threadIdx.x;
    if (i >= RB + RS) return;
    if (i < RB) {
        int id = hid[os[i]];
        os[i] = id;
        atomicAdd(&cntr[id], 1);
    } else {
        int id = hid[TBS + os[i]];
        os[i] = id;
        atomicAdd(&cntr[RB + id], 1);
    }
}

template<int D>
__global__ void build_neighbors(const unsigned long long* __restrict__ uk,
                                const unsigned long long* __restrict__ hk,
                                const int* __restrict__ hid,
                                int tmask, const int* cnt, int stride,
                                int* n1, int* n2) {
    int m = blockIdx.x * blockDim.x + threadIdx.x;
    if (m >= *cnt) return;
    unsigned long long k = uk[m];
    int c[D];
    #pragma unroll
    for (int i = 0; i < D; i++) c[i] = (int)((k >> (12 * i)) & 0xFFFULL) - 2048;
    for (int j = 0; j <= D; j++) {
        unsigned long long p1 = 0, p2 = 0;
        #pragma unroll
        for (int i = 0; i < D; i++) {
            int a = c[i] + ((i == j) ? D : -1);
            int b = c[i] + ((i == j) ? -D : 1);
            p1 |= ((unsigned long long)((unsigned)(a + 2048) & 0xFFFu)) << (12 * i);
            p2 |= ((unsigned long long)((unsigned)(b + 2048) & 0xFFFu)) << (12 * i);
        }
        n1[j * stride + m] = hash_lookup(hk, hid, tmask, p1);
        n2[j * stride + m] = hash_lookup(hk, hid, tmask, p2);
    }
}

// unified fill: epw is one array, offsets are global over RB+RS entries
__global__ void fill_both(const int* __restrict__ os, const float* __restrict__ wsv,
                          const int* __restrict__ off, int* fill, int2* epw) {
    int idx = blockIdx.x * blockDim.x + threadIdx.x;
    if (idx >= RB + RS) return;
    int slot, pix;
    if (idx < RB) { slot = os[idx];        pix = idx / DB1; }
    else          { slot = RB + os[idx];   pix = (idx - RB) / DS1; }
    int pos = off[slot] + atomicAdd(&fill[slot], 1);
    epw[pos] = make_int2(pix, __float_as_int(wsv[idx]));
}

// ---------------- batched filter kernels (fp16 storage, fp32 math) ----------------
__global__ void gather_both_h(const uint2* __restrict__ Qh, const int* __restrict__ off,
                              const int* __restrict__ cntr, const int2* __restrict__ epw,
                              uint2* __restrict__ buf, const int* cnt) {
    int Mb = cnt[0], Ms = cnt[1];
    int totB = (Mb + 1) * CP4;
    int tot = totB + (Ms + 1) * CP4;
    int stride = gridDim.x * blockDim.x;
    for (int idx = blockIdx.x * blockDim.x + threadIdx.x; idx < tot; idx += stride) {
        int c4, o, slot;
        if (idx < totB) {
            int row = idx / CP4; c4 = idx - row * CP4;
            o = idx;
            slot = row ? (row - 1) : -1;
        } else {
            int t = idx - totB;
            int row = t / CP4; c4 = t - row * CP4;
            o = (RB + 1 + row) * CP4 + c4;
            slot = row ? (RB + row - 1) : -1;
        }
        float4 acc = make_float4(0.f, 0.f, 0.f, 0.f);
        if (slot >= 0) {
            int s = off[slot], e = s + cntr[slot];
            for (int t = s; t < e; t++) {
                int2 pw = epw[t];
                float w = __int_as_float(pw.y);
                float4 v = u2f(Qh[(size_t)pw.x * CP4 + c4]);
                acc.x += w * v.x; acc.y += w * v.y; acc.z += w * v.z; acc.w += w * v.w;
            }
        }
        buf[o] = f2u(acc);
    }
}

__global__ void blur_both_h(const uint2* __restrict__ in, uint2* __restrict__ out,
                            const int* __restrict__ n1b, const int* __restrict__ n2b,
                            const int* __restrict__ n1s, const int* __restrict__ n2s,
                            const int* cnt) {
    int Mb = cnt[0], Ms = cnt[1];
    int totB = (Mb + 1) * CP4;
    int tot = totB + (Ms + 1) * CP4;
    int stride = gridDim.x * blockDim.x;
    for (int idx = blockIdx.x * blockDim.x + threadIdx.x; idx < tot; idx += stride) {
        if (idx < totB) {
            int row = idx / CP4, c4 = idx - row * CP4;
            if (row == 0) { out[idx] = make_uint2(0u, 0u); continue; }
            int m = row - 1;
            float4 a = u2f(in[(size_t)(n1b[m] + 1) * CP4 + c4]);
            float4 b = u2f(in[(size_t)(n2b[m] + 1) * CP4 + c4]);
            float4 x = u2f(in[idx]);
            x.x += 0.5f * (a.x + b.x); x.y += 0.5f * (a.y + b.y);
            x.z += 0.5f * (a.z + b.z); x.w += 0.5f * (a.w + b.w);
            out[idx] = f2u(x);
        } else {
            int t = idx - totB;
            int row = t / CP4, c4 = t - row * CP4;
            int o = (RB + 1 + row) * CP4 + c4;
            if (row == 0) { out[o] = make_uint2(0u, 0u); continue; }
            int m = row - 1;
            float4 a = u2f(in[(size_t)(RB + 2 + n1s[m]) * CP4 + c4]);  // -1 -> sink RB+1
            float4 b = u2f(in[(size_t)(RB + 2 + n2s[m]) * CP4 + c4]);
            float4 x = u2f(in[o]);
            x.x += 0.5f * (a.x + b.x); x.y += 0.5f * (a.y + b.y);
            x.z += 0.5f * (a.z + b.z); x.w += 0.5f * (a.w + b.w);
            out[o] = f2u(x);
        }
    }
}

__global__ void blur_b_h(const uint2* __restrict__ in, uint2* __restrict__ out,
                         const int* __restrict__ n1, const int* __restrict__ n2,
                         const int* cnt) {
    int M = cnt[0];
    int total = (M + 1) * CP4;
    int stride = gridDim.x * blockDim.x;
    for (int idx = blockIdx.x * blockDim.x + threadIdx.x; idx < total; idx += stride) {
        int row = idx / CP4, c4 = idx - row * CP4;
        if (row == 0) { out[idx] = make_uint2(0u, 0u); continue; }
        int m = row - 1;
        float4 a = u2f(in[(size_t)(n1[m] + 1) * CP4 + c4]);
        float4 b = u2f(in[(size_t)(n2[m] + 1) * CP4 + c4]);
        float4 x = u2f(in[idx]);
        x.x += 0.5f * (a.x + b.x); x.y += 0.5f * (a.y + b.y);
        x.z += 0.5f * (a.z + b.z); x.w += 0.5f * (a.w + b.w);
        out[idx] = f2u(x);
    }
}

// ---- fp32 norm-chain versions (per-row threads) ----
__global__ void gather1_both(const int* __restrict__ off, const int* __restrict__ cntr,
                             const int2* __restrict__ epw, float* __restrict__ buf,
                             const int* cnt) {
    int Mb = cnt[0], Ms = cnt[1];
    int totB = Mb + 1;
    int tot = totB + Ms + 1;
    int stride = gridDim.x * blockDim.x;
    for (int r = blockIdx.x * blockDim.x + threadIdx.x; r < tot; r += stride) {
        int o, slot;
        if (r < totB) { o = r;              slot = r ? (r - 1) : -1; }
        else          { int t = r - totB; o = RB + 1 + t; slot = t ? (RB + t - 1) : -1; }
        float acc = 0.f;
        if (slot >= 0) {
            int s = off[slot], e = s + cntr[slot];
            for (int t = s; t < e; t++) acc += __int_as_float(epw[t].y);
        }
        buf[o] = acc;
    }
}

__global__ void blur1_both(const float* __restrict__ in, float* __restrict__ out,
                           const int* __restrict__ n1b, const int* __restrict__ n2b,
                           const int* __restrict__ n1s, const int* __restrict__ n2s,
                           const int* cnt) {
    int Mb = cnt[0], Ms = cnt[1];
    int totB = Mb + 1;
    int tot = totB + Ms + 1;
    int stride = gridDim.x * blockDim.x;
    for (int r = blockIdx.x * blockDim.x + threadIdx.x; r < tot; r += stride) {
        if (r < totB) {
            if (r == 0) { out[0] = 0.f; continue; }
            int m = r - 1;
            out[r] = in[r] + 0.5f * (in[n1b[m] + 1] + in[n2b[m] + 1]);
        } else {
            int t = r - totB;
            int o = RB + 1 + t;
            if (t == 0) { out[o] = 0.f; continue; }
            int m = t - 1;
            out[o] = in[o] + 0.5f * (in[RB + 2 + n1s[m]] + in[RB + 2 + n2s[m]]);
        }
    }
}

__global__ void blur1_b(const float* __restrict__ in, float* __restrict__ out,
                        const int* __restrict__ n1, const int* __restrict__ n2,
                        const int* cnt) {
    int M = cnt[0];
    int stride = gridDim.x * blockDim.x;
    for (int row = blockIdx.x * blockDim.x + threadIdx.x; row <= M; row += stride) {
        if (row == 0) { out[0] = 0.f; continue; }
        int m = row - 1;
        out[row] = in[row] + 0.5f * (in[n1[m] + 1] + in[n2[m] + 1]);
    }
}

// both norms in one pass (bilateral final in bufB, spatial final in bufS)
__global__ void slice_norm_both(const float* __restrict__ bufB, const float* __restrict__ bufS,
                                const int* __restrict__ osw, const float* __restrict__ wsv,
                                float* __restrict__ nbv, float* __restrict__ nsv,
                                float alphaB, float alphaS) {
    int i = blockIdx.x * blockDim.x + threadIdx.x;
    if (i >= NPIX) return;
    float sb = 0.f;
    #pragma unroll
    for (int r = 0; r < DB1; r++)
        sb += wsv[i * DB1 + r] * bufB[osw[i * DB1 + r] + 1];
    float ss = 0.f;
    #pragma unroll
    for (int r = 0; r < DS1; r++)
        ss += wsv[RB + i * DS1 + r] * bufS[RB + 2 + osw[RB + i * DS1 + r]];
    nbv[i] = alphaB * sb + 1e-20f;
    nsv[i] = alphaS * ss + 1e-20f;
}

// fused: slice(bilateral)+slice(spatial)+normalize+softmax -> Q (fp32) + Qh (fp16)
__global__ void slice_update(const float* __restrict__ U,
                             const uint2* __restrict__ bufB, const uint2* __restrict__ bufS,
                             const int* __restrict__ osw, const float* __restrict__ wsv,
                             const float* __restrict__ nbv, const float* __restrict__ nsv,
                             float* __restrict__ Q, uint2* __restrict__ Qh,
                             float alphaB, float alphaS, int use_msg) {
    int i = blockIdx.x * blockDim.x + threadIdx.x;
    if (i >= NPIX) return;
    float msg[24];
    #pragma unroll
    for (int t = 0; t < 24; t++) msg[t] = 0.f;
    if (use_msg) {
        float ib = 10.0f * alphaB / nbv[i];
        float is = 3.0f * alphaS / nsv[i];
        #pragma unroll
        for (int r = 0; r < DB1; r++) {
            float w = ib * wsv[i * DB1 + r];
            size_t base = (size_t)(osw[i * DB1 + r] + 1) * CP4;
            #pragma unroll
            for (int t = 0; t < CP4; t++) {
                float4 v = u2f(bufB[base + t]);
                msg[4 * t + 0] += w * v.x; msg[4 * t + 1] += w * v.y;
                msg[4 * t + 2] += w * v.z; msg[4 * t + 3] += w * v.w;
            }
        }
        #pragma unroll
        for (int r = 0; r < DS1; r++) {
            float w = is * wsv[RB + i * DS1 + r];
            size_t base = (size_t)(RB + 2 + osw[RB + i * DS1 + r]) * CP4;
            #pragma unroll
            for (int t = 0; t < CP4; t++) {
                float4 v = u2f(bufS[base + t]);
                msg[4 * t + 0] += w * v.x; msg[4 * t + 1] += w * v.y;
                msg[4 * t + 2] += w * v.z; msg[4 * t + 3] += w * v.w;
            }
        }
    }
    float mx = -1e30f;
    #pragma unroll
    for (int c = 0; c < NC; c++) {
        msg[c] = -U[i * NC + c] + msg[c];
        mx = fmaxf(mx, msg[c]);
    }
    float s = 0.f;
    #pragma unroll
    for (int c = 0; c < NC; c++) { float e = expf(msg[c] - mx); msg[c] = e; s += e; }
    float inv = 1.0f / s;
    #pragma unroll
    for (int c = 0; c < NC; c++) {
        msg[c] *= inv;
        Q[i * NC + c] = msg[c];
    }
    msg[21] = 0.f; msg[22] = 0.f; msg[23] = 0.f;
    #pragma unroll
    for (int t = 0; t < CP4; t++)
        Qh[i * CP4 + t] = f2u(make_float4(msg[4 * t], msg[4 * t + 1], msg[4 * t + 2], msg[4 * t + 3]));
}

// ---------------- host orchestration ----------------
extern "C" void kernel_launch(void* const* d_in, const int* in_sizes, int n_in,
                              void* d_out, int out_size, void* d_ws, size_t ws_size,
                              hipStream_t stream) {
    const float* U     = (const float*)d_in[0];
    const float* image = (const float*)d_in[1];
    float* Q = (float*)d_out;

    char* base = (char*)d_ws;
    size_t off = 0;
    auto alloc = [&](size_t bytes) -> void* {
        off = (off + 255) & ~(size_t)255;
        void* p = base + off; off += bytes; return p;
    };
    // unified per-entry arrays: [0,RB) bilateral, [RB,RB+RS) spatial
    int*   osw  = (int*)  alloc((size_t)(RB + RS) * 4);
    float* wsv  = (float*)alloc((size_t)(RB + RS) * 4);
    int*   n1_b = (int*)  alloc((size_t)DB1 * RB * 4);
    int*   n2_b = (int*)  alloc((size_t)DB1 * RB * 4);
    int*   n1_s = (int*)  alloc((size_t)DS1 * RS * 4);
    int*   n2_s = (int*)  alloc((size_t)DS1 * RS * 4);
    unsigned long long* uk_b = (unsigned long long*)alloc((size_t)RB * 8);
    unsigned long long* uk_s = (unsigned long long*)alloc((size_t)RS * 8);
    unsigned long long* hk = (unsigned long long*)alloc((size_t)(TBS + TSS) * 8);
    int*   hid  = (int*)  alloc((size_t)(TBS + TSS) * 4);
    int*   cnt  = (int*)  alloc(256);   // [0]=M_b, [1]=M_s
    int*   histOff = (int*)alloc((size_t)2 * NBUCK * 4);
    int*   wsums   = (int*)alloc((size_t)64 * 1024 * 4);
    int*   offv    = (int*)alloc((size_t)(RB + RS) * 4);
    // contiguous zero region: cntr | fill | hist | histFill
    char*  zreg  = (char*)alloc((size_t)(RB + RS) * 8 + (size_t)2 * NBUCK * 8);
    int*   cntr     = (int*)zreg;
    int*   fill     = cntr + (RB + RS);
    int*   hist     = fill + (RB + RS);
    int*   histFill = hist + 2 * NBUCK;
    size_t zbytes = (size_t)(RB + RS) * 8 + (size_t)2 * NBUCK * 8;
    int2*  epw  = (int2*) alloc((size_t)(RB + RS) * 8);
    float* norm_b = (float*)alloc((size_t)NPIX * 4);
    float* norm_s = (float*)alloc((size_t)NPIX * 4);
    uint2* Qh   = (uint2*)alloc((size_t)NPIX * CP4 * 8);
    // combined lattice buffers: rows RB+RS+2 (bilateral [0,RB], spatial [RB+1,...])
    uint2* buf0 = (uint2*)alloc((size_t)(RB + RS + 2) * CP4 * 8);
    uint2* buf1 = (uint2*)alloc((size_t)(RB + RS + 2) * CP4 * 8);
    float* nbuf0 = (float*)alloc((size_t)(RB + RS + 2) * 4);
    float* nbuf1 = (float*)alloc((size_t)(RB + RS + 2) * 4);
    if (off > ws_size) return;

    const float ALPHA_B = (float)(1.0 / (1.0 + exp2(-(double)DB)));  // 32/33
    const float ALPHA_S = (float)(1.0 / (1.0 + exp2(-(double)DS)));  // 4/5

    constexpr int PG = 4096;

    // ---- 3 memsets ----
    hipMemsetAsync(cnt, 0, 16, stream);
    hipMemsetAsync(hk, 0xFF, (size_t)(TBS + TSS) * 8, stream);
    hipMemsetAsync(zreg, 0, zbytes, stream);

    // ---- build both lattices ----
    build_both<<<(2 * NPIX + 255) / 256, 256, 0, stream>>>(image, hk, osw, wsv);
    hist_both<<<(TBS + TSS) / 256, 256, 0, stream>>>(hk, hist);
    // compaction scans per table (ids start at 0 for each)
    scan_wave_partial<<<NBUCK / 256, 256, 0, stream>>>(hist, histOff, wsums, NBUCK);
    scan_partials_excl<<<1, 256, 0, stream>>>(wsums, NBUCK / 64, cnt + 0);
    scan_finalize<<<NBUCK / 256, 256, 0, stream>>>(histOff, hist, wsums, NBUCK);
    scan_wave_partial<<<NBUCK / 256, 256, 0, stream>>>(hist + NBUCK, histOff + NBUCK, wsums, NBUCK);
    scan_partials_excl<<<1, 256, 0, stream>>>(wsums, NBUCK / 64, cnt + 1);
    scan_finalize<<<NBUCK / 256, 256, 0, stream>>>(histOff + NBUCK, hist + NBUCK, wsums, NBUCK);
    assign_both<<<(TBS + TSS) / 256, 256, 0, stream>>>(hk, hid, histOff, histFill, uk_b, uk_s);
    os_count_both<<<(RB + RS) / 256, 256, 0, stream>>>(osw, hid, cntr);
    build_neighbors<DB><<<(RB + 255) / 256, 256, 0, stream>>>(uk_b, hk, hid, TBS - 1, cnt + 0, RB, n1_b, n2_b);
    build_neighbors<DS><<<(RS + 255) / 256, 256, 0, stream>>>(uk_s, hk + TBS, hid + TBS, TSS - 1, cnt + 1, RS, n1_s, n2_s);
    // unified offset scan over RB+RS id slots
    scan_wave_partial<<<(RB + RS) / 256, 256, 0, stream>>>(cntr, offv, wsums, RB + RS);
    scan_partials_excl<<<1, 256, 0, stream>>>(wsums, (RB + RS) / 64, nullptr);
    scan_finalize<<<(RB + RS) / 256, 256, 0, stream>>>(offv, cntr, wsums, RB + RS);
    fill_both<<<(RB + RS + 255) / 256, 256, 0, stream>>>(osw, wsv, offv, fill, epw);

    // ---- norm filters (C=1, fp32), batched ----
    {
        gather1_both<<<1024, 256, 0, stream>>>(offv, cntr, epw, nbuf0, cnt);
        float* a = nbuf0; float* b = nbuf1;
        for (int j = 0; j < DS1; j++) {   // j=0..2: both chains
            blur1_both<<<1024, 256, 0, stream>>>(a, b,
                n1_b + (size_t)j * RB, n2_b + (size_t)j * RB,
                n1_s + (size_t)j * RS, n2_s + (size_t)j * RS, cnt);
            float* t = a; a = b; b = t;
        }
        // spatial final now in a's spatial region... after 3 swaps a==nbuf1.
        // j=3..5: bilateral only — writes only rows [0,Mb], spatial region of each
        // target buffer is stale but never written; spatial final stays in nbuf1.
        for (int j = DS1; j < DB1; j++) {
            blur1_b<<<1024, 256, 0, stream>>>(a, b, n1_b + (size_t)j * RB, n2_b + (size_t)j * RB, cnt);
            float* t = a; a = b; b = t;
        }
        // bilateral final in nbuf0 (6 swaps), spatial final in nbuf1 (3 swaps)
        slice_norm_both<<<(NPIX + 255) / 256, 256, 0, stream>>>(
            nbuf0, nbuf1, osw, wsv, norm_b, norm_s, ALPHA_B, ALPHA_S);
    }

    // ---- Q0 = softmax(-U) ----
    slice_update<<<(NPIX + 255) / 256, 256, 0, stream>>>(
        U, buf0, buf1, osw, wsv, norm_b, norm_s, Q, Qh, ALPHA_B, ALPHA_S, 0);

    // ---- 5 mean-field iterations ----
    for (int it = 0; it < 5; it++) {
        gather_both_h<<<PG, 256, 0, stream>>>(Qh, offv, cntr, epw, buf0, cnt);
        uint2* a = buf0; uint2* b = buf1;
        for (int j = 0; j < DS1; j++) {   // j=0..2: both chains in one launch
            blur_both_h<<<PG, 256, 0, stream>>>(a, b,
                n1_b + (size_t)j * RB, n2_b + (size_t)j * RB,
                n1_s + (size_t)j * RS, n2_s + (size_t)j * RS, cnt);
            uint2* t = a; a = b; b = t;
        }
        for (int j = DS1; j < DB1; j++) { // j=3..5: bilateral only
            blur_b_h<<<PG, 256, 0, stream>>>(a, b, n1_b + (size_t)j * RB, n2_b + (size_t)j * RB, cnt);
            uint2* t = a; a = b; b = t;
        }
        // bilateral final in buf0, spatial final in buf1 (see norm-chain comment)
        slice_update<<<(NPIX + 255) / 256, 256, 0, stream>>>(
            U, buf0, buf1, osw, wsv, norm_b, norm_s, Q, Qh, ALPHA_B, ALPHA_S, 1);
    }
}

// Round 11
// 982.884 us; speedup vs baseline: 1.3425x; 1.0522x over previous
//
#include <hip/hip_runtime.h>
#include <hip/hip_fp16.h>
#include <cmath>

// ---------------- problem constants ----------------
constexpr int IMH = 320, IMW = 320, NPIX = IMH * IMW, NC = 21;
constexpr int CP4 = 6;           // padded channels / 4  (24 values per row)
constexpr int DB = 5, DB1 = 6;   // bilateral lattice dim
constexpr int DS = 2, DS1 = 3;   // spatial lattice dim
constexpr int RB = NPIX * DB1;   // splat entries (bilateral) = 614400
constexpr int RS = NPIX * DS1;   // (spatial) = 307200
constexpr int TBS = 1 << 20;     // hash table slots (bilateral)
constexpr int TSS = 1 << 18;     // hash table slots (spatial)
constexpr int NBUCK = 1 << 16;   // spatial-sort buckets (c0,c1 low bytes)
constexpr int NW1 = (RB + RS) / 64;  // 14400 wave sums in the unified offset scan

// Combined lattice-value buffer layout (static partition):
//   bilateral: row 0 = sink, point m -> row m+1           (rows [0, RB])
//   spatial:   row RB+1 = sink, point m -> row RB+2+m     (rows [RB+1, ...])
// spatial neighbor n=-1 maps to RB+2+(-1) = RB+1 = sink automatically.

#define EMPTY_KEY 0xFFFFFFFFFFFFFFFFULL

__device__ __forceinline__ unsigned long long mix64(unsigned long long x) {
    x ^= x >> 33; x *= 0xff51afd7ed558ccdULL;
    x ^= x >> 33; x *= 0xc4ceb9fe1a85ec53ULL;
    x ^= x >> 33; return x;
}

// fp16 pack helpers: uint2 = 4 halves; math in fp32, storage fp16.
__device__ __forceinline__ float4 u2f(uint2 u) {
    __half2 a = *reinterpret_cast<__half2*>(&u.x);
    __half2 b = *reinterpret_cast<__half2*>(&u.y);
    float2 fa = __half22float2(a), fb = __half22float2(b);
    return make_float4(fa.x, fa.y, fb.x, fb.y);
}
__device__ __forceinline__ uint2 f2u(float4 v) {
    __half2 a = __floats2half2_rn(v.x, v.y);
    __half2 b = __floats2half2_rn(v.z, v.w);
    uint2 u;
    u.x = *reinterpret_cast<unsigned*>(&a);
    u.y = *reinterpret_cast<unsigned*>(&b);
    return u;
}

// ---------------- permutohedral embedding (matches reference op-for-op, f32) ----------------
template<int D>
__device__ void perm_embed(const float* f, float* bary, unsigned long long* pk) {
    constexpr int D1 = D + 1;
    float cf[D];
    #pragma unroll
    for (int i = 0; i < D; i++) {
        double s = sqrt(2.0 / 3.0) * (double)D1 / sqrt((double)((i + 1) * (i + 2)));
        cf[i] = f[i] * (float)s;
    }
    float csum[D];
    float acc = 0.f;
    #pragma unroll
    for (int i = D - 1; i >= 0; i--) { acc += cf[i]; csum[i] = acc; }
    float el[D1];
    el[0] = csum[0];
    #pragma unroll
    for (int i = 1; i < D; i++) el[i] = csum[i] - (float)i * cf[i - 1];
    el[D] = -(float)D * cf[D - 1];
    const float down = 1.0f / (float)D1;
    float rem0[D1]; int rank[D1]; int ssum = 0;
    #pragma unroll
    for (int i = 0; i < D1; i++) {
        float rd = rintf(el[i] * down);
        rem0[i] = rd * (float)D1;
        ssum += (int)rd;
    }
    float diff[D1];
    #pragma unroll
    for (int i = 0; i < D1; i++) diff[i] = el[i] - rem0[i];
    #pragma unroll
    for (int i = 0; i < D1; i++) {
        int r = 0;
        #pragma unroll
        for (int j = 0; j < D1; j++)
            r += (diff[j] > diff[i]) || ((diff[j] == diff[i]) && (j < i));
        rank[i] = r + ssum;
    }
    #pragma unroll
    for (int i = 0; i < D1; i++) {
        if (rank[i] < 0)      { rank[i] += D1; rem0[i] += (float)D1; }
        else if (rank[i] > D) { rank[i] -= D1; rem0[i] -= (float)D1; }
    }
    float b[D + 2];
    #pragma unroll
    for (int i = 0; i < D + 2; i++) b[i] = 0.f;
    #pragma unroll
    for (int i = 0; i < D1; i++) b[D - rank[i]]     += (el[i] - rem0[i]) * down;
    #pragma unroll
    for (int i = 0; i < D1; i++) b[D + 1 - rank[i]] -= (el[i] - rem0[i]) * down;
    b[0] += 1.0f + b[D + 1];
    #pragma unroll
    for (int i = 0; i < D1; i++) bary[i] = b[i];
    int key0[D];
    #pragma unroll
    for (int i = 0; i < D; i++) key0[i] = (int)rintf(rem0[i]);
    #pragma unroll
    for (int r = 0; r < D1; r++) {
        unsigned long long p = 0;
        #pragma unroll
        for (int i = 0; i < D; i++) {
            int c = key0[i] + ((rank[i] < D1 - r) ? r : r - D1);
            p |= ((unsigned long long)((unsigned)(c + 2048) & 0xFFFu)) << (12 * i);
        }
        pk[r] = p;
    }
}

// ---------------- hash table ----------------
__device__ __forceinline__ int hash_insert(unsigned long long* hk, int tmask, unsigned long long k) {
    int slot = (int)(mix64(k) & (unsigned long long)tmask);
    while (true) {
        unsigned long long prev = atomicCAS(&hk[slot], EMPTY_KEY, k);
        if (prev == EMPTY_KEY || prev == k) return slot;
        slot = (slot + 1) & tmask;
    }
}
__device__ __forceinline__ int hash_lookup(const unsigned long long* hk, const int* hid,
                                           int tmask, unsigned long long k) {
    int slot = (int)(mix64(k) & (unsigned long long)tmask);
    while (true) {
        unsigned long long v = hk[slot];
        if (v == k) return hid[slot];
        if (v == EMPTY_KEY) return -1;
        slot = (slot + 1) & tmask;
    }
}

__device__ __forceinline__ int key_code(unsigned long long k) {
    int c0 = (int)(k & 0xFFFULL);
    int c1 = (int)((k >> 12) & 0xFFFULL);
    return ((c0 & 0xFF) << 8) | (c1 & 0xFF);
}

// ---------------- build kernels ----------------
// one launch builds both lattices (hk = unified table: [0,TBS) bilateral, [TBS,TBS+TSS) spatial)
__global__ void build_both(const float* __restrict__ image, unsigned long long* hk,
                           int* os, float* wsv) {
    int i = blockIdx.x * blockDim.x + threadIdx.x;
    if (i < NPIX) {
        int x = i % IMW, y = i / IMW;
        float f[DB];
        f[0] = (float)x / 80.0f;
        f[1] = (float)y / 80.0f;
        f[2] = image[i * 3 + 0] / 13.0f;
        f[3] = image[i * 3 + 1] / 13.0f;
        f[4] = image[i * 3 + 2] / 13.0f;
        float bary[DB1]; unsigned long long pk[DB1];
        perm_embed<DB>(f, bary, pk);
        #pragma unroll
        for (int r = 0; r < DB1; r++) {
            wsv[i * DB1 + r] = bary[r];
            os[i * DB1 + r] = hash_insert(hk, TBS - 1, pk[r]);   // local slot in table b
        }
    } else if (i < 2 * NPIX) {
        int ip = i - NPIX;
        int x = ip % IMW, y = ip / IMW;
        float f[DS];
        f[0] = (float)x / 3.0f;
        f[1] = (float)y / 3.0f;
        float bary[DS1]; unsigned long long pk[DS1];
        perm_embed<DS>(f, bary, pk);
        #pragma unroll
        for (int r = 0; r < DS1; r++) {
            wsv[RB + ip * DS1 + r] = bary[r];
            os[RB + ip * DS1 + r] = hash_insert(hk + TBS, TSS - 1, pk[r]);  // local slot
        }
    }
}

// ---------------- barrier-free scan machinery ----------------
__global__ void scan_wave_partial(const int* __restrict__ count, int* incl, int* wsum, int n) {
    int idx = blockIdx.x * blockDim.x + threadIdx.x;
    int lane = threadIdx.x & 63;
    int v = (idx < n) ? count[idx] : 0;
    int s = v;
    #pragma unroll
    for (int d = 1; d < 64; d <<= 1) {
        int t = __shfl_up(s, d);
        if (lane >= d) s += t;
    }
    if (idx < n) incl[idx] = s;
    if (lane == 63) wsum[idx >> 6] = s;
}

__global__ void scan_partials_excl(int* w, int nw, int* total_out) {
    __shared__ int sh[256];
    __shared__ int run;
    if (threadIdx.x == 0) run = 0;
    __syncthreads();
    for (int basei = 0; basei < nw; basei += 256) {
        int idx = basei + threadIdx.x;
        int v = (idx < nw) ? w[idx] : 0;
        sh[threadIdx.x] = v;
        __syncthreads();
        for (int d = 1; d < 256; d <<= 1) {
            int t = (threadIdx.x >= d) ? sh[threadIdx.x - d] : 0;
            __syncthreads();
            sh[threadIdx.x] += t;
            __syncthreads();
        }
        int total = sh[255];
        if (idx < nw) w[idx] = run + sh[threadIdx.x] - v;
        __syncthreads();
        if (threadIdx.x == 0) run += total;
        __syncthreads();
    }
    if (total_out != nullptr && threadIdx.x == 0) *total_out = run;
}

__global__ void scan_finalize(int* off, const int* __restrict__ count,
                              const int* __restrict__ wsum, int n) {
    int idx = blockIdx.x * blockDim.x + threadIdx.x;
    if (idx < n) off[idx] = off[idx] - count[idx] + wsum[idx >> 6];
}

// ---------------- bucket-sorted compaction ----------------
// hist over BOTH tables in one pass (hist halves: [0,NBUCK) b, [NBUCK,2N) s)
__global__ void hist_both(const unsigned long long* __restrict__ hk, int* hist) {
    int s = blockIdx.x * blockDim.x + threadIdx.x;
    if (s >= TBS + TSS) return;
    unsigned long long k = hk[s];
    if (k == EMPTY_KEY) return;
    int half = (s < TBS) ? 0 : NBUCK;
    atomicAdd(&hist[half + key_code(k)], 1);
}

__global__ void assign_both(const unsigned long long* __restrict__ hk, int* hid,
                            const int* __restrict__ histOff, int* histFill,
                            unsigned long long* uk_b, unsigned long long* uk_s) {
    int s = blockIdx.x * blockDim.x + threadIdx.x;
    if (s >= TBS + TSS) return;
    unsigned long long k = hk[s];
    if (k == EMPTY_KEY) return;
    int half = (s < TBS) ? 0 : NBUCK;
    int code = half + key_code(k);
    int id = histOff[code] + atomicAdd(&histFill[code], 1);
    hid[s] = id;
    if (s < TBS) uk_b[id] = k; else uk_s[id] = k;
}

// unified os remap + cntr histogram (cntr slots: [0,RB) bilateral ids, [RB,RB+RS) spatial)
__global__ void os_count_both(int* os, const int* __restrict__ hid, int* cntr) {
    int i = blockIdx.x * blockDim.x + threadIdx.x;
    if (i >= RB + RS) return;
    if (i < RB) {
        int id = hid[os[i]];
        os[i] = id;
        atomicAdd(&cntr[id], 1);
    } else {
        int id = hid[TBS + os[i]];
        os[i] = id;
        atomicAdd(&cntr[RB + id], 1);
    }
}

template<int D>
__global__ void build_neighbors(const unsigned long long* __restrict__ uk,
                                const unsigned long long* __restrict__ hk,
                                const int* __restrict__ hid,
                                int tmask, const int* cnt, int stride,
                                int* n1, int* n2) {
    int m = blockIdx.x * blockDim.x + threadIdx.x;
    if (m >= *cnt) return;
    unsigned long long k = uk[m];
    int c[D];
    #pragma unroll
    for (int i = 0; i < D; i++) c[i] = (int)((k >> (12 * i)) & 0xFFFULL) - 2048;
    for (int j = 0; j <= D; j++) {
        unsigned long long p1 = 0, p2 = 0;
        #pragma unroll
        for (int i = 0; i < D; i++) {
            int a = c[i] + ((i == j) ? D : -1);
            int b = c[i] + ((i == j) ? -D : 1);
            p1 |= ((unsigned long long)((unsigned)(a + 2048) & 0xFFFu)) << (12 * i);
            p2 |= ((unsigned long long)((unsigned)(b + 2048) & 0xFFFu)) << (12 * i);
        }
        n1[j * stride + m] = hash_lookup(hk, hid, tmask, p1);
        n2[j * stride + m] = hash_lookup(hk, hid, tmask, p2);
    }
}

// unified fill: epw is one array, offsets are global over RB+RS entries
__global__ void fill_both(const int* __restrict__ os, const float* __restrict__ wsv,
                          const int* __restrict__ off, int* fill, int2* epw) {
    int idx = blockIdx.x * blockDim.x + threadIdx.x;
    if (idx >= RB + RS) return;
    int slot, pix;
    if (idx < RB) { slot = os[idx];        pix = idx / DB1; }
    else          { slot = RB + os[idx];   pix = (idx - RB) / DS1; }
    int pos = off[slot] + atomicAdd(&fill[slot], 1);
    epw[pos] = make_int2(pix, __float_as_int(wsv[idx]));
}

// ---------------- batched filter kernels (fp16 storage, fp32 math) ----------------
__global__ void gather_both_h(const uint2* __restrict__ Qh, const int* __restrict__ off,
                              const int* __restrict__ cntr, const int2* __restrict__ epw,
                              uint2* __restrict__ buf, const int* cnt) {
    int Mb = cnt[0], Ms = cnt[1];
    int totB = (Mb + 1) * CP4;
    int tot = totB + (Ms + 1) * CP4;
    int stride = gridDim.x * blockDim.x;
    for (int idx = blockIdx.x * blockDim.x + threadIdx.x; idx < tot; idx += stride) {
        int c4, o, slot;
        if (idx < totB) {
            int row = idx / CP4; c4 = idx - row * CP4;
            o = idx;
            slot = row ? (row - 1) : -1;
        } else {
            int t = idx - totB;
            int row = t / CP4; c4 = t - row * CP4;
            o = (RB + 1 + row) * CP4 + c4;
            slot = row ? (RB + row - 1) : -1;
        }
        float4 acc = make_float4(0.f, 0.f, 0.f, 0.f);
        if (slot >= 0) {
            int s = off[slot], e = s + cntr[slot];
            for (int t = s; t < e; t++) {
                int2 pw = epw[t];
                float w = __int_as_float(pw.y);
                float4 v = u2f(Qh[(size_t)pw.x * CP4 + c4]);
                acc.x += w * v.x; acc.y += w * v.y; acc.z += w * v.z; acc.w += w * v.w;
            }
        }
        buf[o] = f2u(acc);
    }
}

__global__ void blur_both_h(const uint2* __restrict__ in, uint2* __restrict__ out,
                            const int* __restrict__ n1b, const int* __restrict__ n2b,
                            const int* __restrict__ n1s, const int* __restrict__ n2s,
                            const int* cnt) {
    int Mb = cnt[0], Ms = cnt[1];
    int totB = (Mb + 1) * CP4;
    int tot = totB + (Ms + 1) * CP4;
    int stride = gridDim.x * blockDim.x;
    for (int idx = blockIdx.x * blockDim.x + threadIdx.x; idx < tot; idx += stride) {
        if (idx < totB) {
            int row = idx / CP4, c4 = idx - row * CP4;
            if (row == 0) { out[idx] = make_uint2(0u, 0u); continue; }
            int m = row - 1;
            float4 a = u2f(in[(size_t)(n1b[m] + 1) * CP4 + c4]);
            float4 b = u2f(in[(size_t)(n2b[m] + 1) * CP4 + c4]);
            float4 x = u2f(in[idx]);
            x.x += 0.5f * (a.x + b.x); x.y += 0.5f * (a.y + b.y);
            x.z += 0.5f * (a.z + b.z); x.w += 0.5f * (a.w + b.w);
            out[idx] = f2u(x);
        } else {
            int t = idx - totB;
            int row = t / CP4, c4 = t - row * CP4;
            int o = (RB + 1 + row) * CP4 + c4;
            if (row == 0) { out[o] = make_uint2(0u, 0u); continue; }
            int m = row - 1;
            float4 a = u2f(in[(size_t)(RB + 2 + n1s[m]) * CP4 + c4]);  // -1 -> sink RB+1
            float4 b = u2f(in[(size_t)(RB + 2 + n2s[m]) * CP4 + c4]);
            float4 x = u2f(in[o]);
            x.x += 0.5f * (a.x + b.x); x.y += 0.5f * (a.y + b.y);
            x.z += 0.5f * (a.z + b.z); x.w += 0.5f * (a.w + b.w);
            out[o] = f2u(x);
        }
    }
}

__global__ void blur_b_h(const uint2* __restrict__ in, uint2* __restrict__ out,
                         const int* __restrict__ n1, const int* __restrict__ n2,
                         const int* cnt) {
    int M = cnt[0];
    int total = (M + 1) * CP4;
    int stride = gridDim.x * blockDim.x;
    for (int idx = blockIdx.x * blockDim.x + threadIdx.x; idx < total; idx += stride) {
        int row = idx / CP4, c4 = idx - row * CP4;
        if (row == 0) { out[idx] = make_uint2(0u, 0u); continue; }
        int m = row - 1;
        float4 a = u2f(in[(size_t)(n1[m] + 1) * CP4 + c4]);
        float4 b = u2f(in[(size_t)(n2[m] + 1) * CP4 + c4]);
        float4 x = u2f(in[idx]);
        x.x += 0.5f * (a.x + b.x); x.y += 0.5f * (a.y + b.y);
        x.z += 0.5f * (a.z + b.z); x.w += 0.5f * (a.w + b.w);
        out[idx] = f2u(x);
    }
}

// ---- fp32 norm-chain versions (per-row threads) ----
__global__ void gather1_both(const int* __restrict__ off, const int* __restrict__ cntr,
                             const int2* __restrict__ epw, float* __restrict__ buf,
                             const int* cnt) {
    int Mb = cnt[0], Ms = cnt[1];
    int totB = Mb + 1;
    int tot = totB + Ms + 1;
    int stride = gridDim.x * blockDim.x;
    for (int r = blockIdx.x * blockDim.x + threadIdx.x; r < tot; r += stride) {
        int o, slot;
        if (r < totB) { o = r;              slot = r ? (r - 1) : -1; }
        else          { int t = r - totB; o = RB + 1 + t; slot = t ? (RB + t - 1) : -1; }
        float acc = 0.f;
        if (slot >= 0) {
            int s = off[slot], e = s + cntr[slot];
            for (int t = s; t < e; t++) acc += __int_as_float(epw[t].y);
        }
        buf[o] = acc;
    }
}

__global__ void blur1_both(const float* __restrict__ in, float* __restrict__ out,
                           const int* __restrict__ n1b, const int* __restrict__ n2b,
                           const int* __restrict__ n1s, const int* __restrict__ n2s,
                           const int* cnt) {
    int Mb = cnt[0], Ms = cnt[1];
    int totB = Mb + 1;
    int tot = totB + Ms + 1;
    int stride = gridDim.x * blockDim.x;
    for (int r = blockIdx.x * blockDim.x + threadIdx.x; r < tot; r += stride) {
        if (r < totB) {
            if (r == 0) { out[0] = 0.f; continue; }
            int m = r - 1;
            out[r] = in[r] + 0.5f * (in[n1b[m] + 1] + in[n2b[m] + 1]);
        } else {
            int t = r - totB;
            int o = RB + 1 + t;
            if (t == 0) { out[o] = 0.f; continue; }
            int m = t - 1;
            out[o] = in[o] + 0.5f * (in[RB + 2 + n1s[m]] + in[RB + 2 + n2s[m]]);
        }
    }
}

__global__ void blur1_b(const float* __restrict__ in, float* __restrict__ out,
                        const int* __restrict__ n1, const int* __restrict__ n2,
                        const int* cnt) {
    int M = cnt[0];
    int stride = gridDim.x * blockDim.x;
    for (int row = blockIdx.x * blockDim.x + threadIdx.x; row <= M; row += stride) {
        if (row == 0) { out[0] = 0.f; continue; }
        int m = row - 1;
        out[row] = in[row] + 0.5f * (in[n1[m] + 1] + in[n2[m] + 1]);
    }
}

// both norms in one pass (bilateral final in bufB, spatial final in bufS)
__global__ void slice_norm_both(const float* __restrict__ bufB, const float* __restrict__ bufS,
                                const int* __restrict__ osw, const float* __restrict__ wsv,
                                float* __restrict__ nbv, float* __restrict__ nsv,
                                float alphaB, float alphaS) {
    int i = blockIdx.x * blockDim.x + threadIdx.x;
    if (i >= NPIX) return;
    float sb = 0.f;
    #pragma unroll
    for (int r = 0; r < DB1; r++)
        sb += wsv[i * DB1 + r] * bufB[osw[i * DB1 + r] + 1];
    float ss = 0.f;
    #pragma unroll
    for (int r = 0; r < DS1; r++)
        ss += wsv[RB + i * DS1 + r] * bufS[RB + 2 + osw[RB + i * DS1 + r]];
    nbv[i] = alphaB * sb + 1e-20f;
    nsv[i] = alphaS * ss + 1e-20f;
}

// fused: slice(bilateral)+slice(spatial)+normalize+softmax -> Q (fp32) + Qh (fp16)
__global__ void slice_update(const float* __restrict__ U,
                             const uint2* __restrict__ bufB, const uint2* __restrict__ bufS,
                             const int* __restrict__ osw, const float* __restrict__ wsv,
                             const float* __restrict__ nbv, const float* __restrict__ nsv,
                             float* __restrict__ Q, uint2* __restrict__ Qh,
                             float alphaB, float alphaS, int use_msg) {
    int i = blockIdx.x * blockDim.x + threadIdx.x;
    if (i >= NPIX) return;
    float msg[24];
    #pragma unroll
    for (int t = 0; t < 24; t++) msg[t] = 0.f;
    if (use_msg) {
        float ib = 10.0f * alphaB / nbv[i];
        float is = 3.0f * alphaS / nsv[i];
        #pragma unroll
        for (int r = 0; r < DB1; r++) {
            float w = ib * wsv[i * DB1 + r];
            size_t base = (size_t)(osw[i * DB1 + r] + 1) * CP4;
            #pragma unroll
            for (int t = 0; t < CP4; t++) {
                float4 v = u2f(bufB[base + t]);
                msg[4 * t + 0] += w * v.x; msg[4 * t + 1] += w * v.y;
                msg[4 * t + 2] += w * v.z; msg[4 * t + 3] += w * v.w;
            }
        }
        #pragma unroll
        for (int r = 0; r < DS1; r++) {
            float w = is * wsv[RB + i * DS1 + r];
            size_t base = (size_t)(RB + 2 + osw[RB + i * DS1 + r]) * CP4;
            #pragma unroll
            for (int t = 0; t < CP4; t++) {
                float4 v = u2f(bufS[base + t]);
                msg[4 * t + 0] += w * v.x; msg[4 * t + 1] += w * v.y;
                msg[4 * t + 2] += w * v.z; msg[4 * t + 3] += w * v.w;
            }
        }
    }
    float mx = -1e30f;
    #pragma unroll
    for (int c = 0; c < NC; c++) {
        msg[c] = -U[i * NC + c] + msg[c];
        mx = fmaxf(mx, msg[c]);
    }
    float s = 0.f;
    #pragma unroll
    for (int c = 0; c < NC; c++) { float e = expf(msg[c] - mx); msg[c] = e; s += e; }
    float inv = 1.0f / s;
    #pragma unroll
    for (int c = 0; c < NC; c++) {
        msg[c] *= inv;
        Q[i * NC + c] = msg[c];
    }
    msg[21] = 0.f; msg[22] = 0.f; msg[23] = 0.f;
    #pragma unroll
    for (int t = 0; t < CP4; t++)
        Qh[i * CP4 + t] = f2u(make_float4(msg[4 * t], msg[4 * t + 1], msg[4 * t + 2], msg[4 * t + 3]));
}

// ---------------- host orchestration ----------------
extern "C" void kernel_launch(void* const* d_in, const int* in_sizes, int n_in,
                              void* d_out, int out_size, void* d_ws, size_t ws_size,
                              hipStream_t stream) {
    const float* U     = (const float*)d_in[0];
    const float* image = (const float*)d_in[1];
    float* Q = (float*)d_out;

    char* base = (char*)d_ws;
    size_t off = 0;
    auto alloc = [&](size_t bytes) -> void* {
        off = (off + 255) & ~(size_t)255;
        void* p = base + off; off += bytes; return p;
    };
    // unified per-entry arrays: [0,RB) bilateral, [RB,RB+RS) spatial
    int*   osw  = (int*)  alloc((size_t)(RB + RS) * 4);
    float* wsv  = (float*)alloc((size_t)(RB + RS) * 4);
    int*   n1_b = (int*)  alloc((size_t)DB1 * RB * 4);
    int*   n2_b = (int*)  alloc((size_t)DB1 * RB * 4);
    int*   n1_s = (int*)  alloc((size_t)DS1 * RS * 4);
    int*   n2_s = (int*)  alloc((size_t)DS1 * RS * 4);
    unsigned long long* uk_b = (unsigned long long*)alloc((size_t)RB * 8);
    unsigned long long* uk_s = (unsigned long long*)alloc((size_t)RS * 8);
    unsigned long long* hk = (unsigned long long*)alloc((size_t)(TBS + TSS) * 8);
    int*   hid  = (int*)  alloc((size_t)(TBS + TSS) * 4);
    int*   cnt  = (int*)  alloc(256);   // [0]=M_b, [1]=M_s
    int*   histOff = (int*)alloc((size_t)2 * NBUCK * 4);
    int*   wsums   = (int*)alloc((size_t)64 * 1024 * 4);
    int*   wsI     = (int*)alloc((size_t)16384 * 4);   // level-1 inclusive sums
    int*   ws2     = (int*)alloc((size_t)1024 * 4);    // level-2 sums
    int*   offv    = (int*)alloc((size_t)(RB + RS) * 4);
    // contiguous zero region: cntr | fill | hist | histFill
    char*  zreg  = (char*)alloc((size_t)(RB + RS) * 8 + (size_t)2 * NBUCK * 8);
    int*   cntr     = (int*)zreg;
    int*   fill     = cntr + (RB + RS);
    int*   hist     = fill + (RB + RS);
    int*   histFill = hist + 2 * NBUCK;
    size_t zbytes = (size_t)(RB + RS) * 8 + (size_t)2 * NBUCK * 8;
    int2*  epw  = (int2*) alloc((size_t)(RB + RS) * 8);
    float* norm_b = (float*)alloc((size_t)NPIX * 4);
    float* norm_s = (float*)alloc((size_t)NPIX * 4);
    uint2* Qh   = (uint2*)alloc((size_t)NPIX * CP4 * 8);
    // combined lattice buffers: rows RB+RS+2 (bilateral [0,RB], spatial [RB+1,...])
    uint2* buf0 = (uint2*)alloc((size_t)(RB + RS + 2) * CP4 * 8);
    uint2* buf1 = (uint2*)alloc((size_t)(RB + RS + 2) * CP4 * 8);
    float* nbuf0 = (float*)alloc((size_t)(RB + RS + 2) * 4);
    float* nbuf1 = (float*)alloc((size_t)(RB + RS + 2) * 4);
    if (off > ws_size) return;

    const float ALPHA_B = (float)(1.0 / (1.0 + exp2(-(double)DB)));  // 32/33
    const float ALPHA_S = (float)(1.0 / (1.0 + exp2(-(double)DS)));  // 4/5

    constexpr int PG = 4096;

    // ---- 3 memsets ----
    hipMemsetAsync(cnt, 0, 16, stream);
    hipMemsetAsync(hk, 0xFF, (size_t)(TBS + TSS) * 8, stream);
    hipMemsetAsync(zreg, 0, zbytes, stream);

    // ---- build both lattices ----
    build_both<<<(2 * NPIX + 255) / 256, 256, 0, stream>>>(image, hk, osw, wsv);
    hist_both<<<(TBS + TSS) / 256, 256, 0, stream>>>(hk, hist);
    // compaction scans per table (ids start at 0 for each)
    scan_wave_partial<<<NBUCK / 256, 256, 0, stream>>>(hist, histOff, wsums, NBUCK);
    scan_partials_excl<<<1, 256, 0, stream>>>(wsums, NBUCK / 64, cnt + 0);
    scan_finalize<<<NBUCK / 256, 256, 0, stream>>>(histOff, hist, wsums, NBUCK);
    scan_wave_partial<<<NBUCK / 256, 256, 0, stream>>>(hist + NBUCK, histOff + NBUCK, wsums, NBUCK);
    scan_partials_excl<<<1, 256, 0, stream>>>(wsums, NBUCK / 64, cnt + 1);
    scan_finalize<<<NBUCK / 256, 256, 0, stream>>>(histOff + NBUCK, hist + NBUCK, wsums, NBUCK);
    assign_both<<<(TBS + TSS) / 256, 256, 0, stream>>>(hk, hid, histOff, histFill, uk_b, uk_s);
    os_count_both<<<(RB + RS) / 256, 256, 0, stream>>>(osw, hid, cntr);
    build_neighbors<DB><<<(RB + 255) / 256, 256, 0, stream>>>(uk_b, hk, hid, TBS - 1, cnt + 0, RB, n1_b, n2_b);
    build_neighbors<DS><<<(RS + 255) / 256, 256, 0, stream>>>(uk_s, hk + TBS, hid + TBS, TSS - 1, cnt + 1, RS, n1_s, n2_s);
    // unified offset scan over RB+RS id slots — HIERARCHICAL (the single-block
    // scan of 14400 wave sums was 65 us in r10; now only 225 entries are serial)
    scan_wave_partial<<<(RB + RS) / 256, 256, 0, stream>>>(cntr, offv, wsums, RB + RS);
    scan_wave_partial<<<(NW1 + 255) / 256, 256, 0, stream>>>(wsums, wsI, ws2, NW1);
    scan_partials_excl<<<1, 256, 0, stream>>>(ws2, (NW1 + 63) / 64, nullptr);
    scan_finalize<<<(NW1 + 255) / 256, 256, 0, stream>>>(wsI, wsums, ws2, NW1);
    scan_finalize<<<(RB + RS) / 256, 256, 0, stream>>>(offv, cntr, wsI, RB + RS);
    fill_both<<<(RB + RS + 255) / 256, 256, 0, stream>>>(osw, wsv, offv, fill, epw);

    // ---- norm filters (C=1, fp32), batched ----
    {
        gather1_both<<<1024, 256, 0, stream>>>(offv, cntr, epw, nbuf0, cnt);
        float* a = nbuf0; float* b = nbuf1;
        for (int j = 0; j < DS1; j++) {   // j=0..2: both chains
            blur1_both<<<1024, 256, 0, stream>>>(a, b,
                n1_b + (size_t)j * RB, n2_b + (size_t)j * RB,
                n1_s + (size_t)j * RS, n2_s + (size_t)j * RS, cnt);
            float* t = a; a = b; b = t;
        }
        // j=3..5: bilateral only — writes only rows [0,Mb]; spatial final stays in nbuf1.
        for (int j = DS1; j < DB1; j++) {
            blur1_b<<<1024, 256, 0, stream>>>(a, b, n1_b + (size_t)j * RB, n2_b + (size_t)j * RB, cnt);
            float* t = a; a = b; b = t;
        }
        // bilateral final in nbuf0 (6 swaps), spatial final in nbuf1 (3 swaps)
        slice_norm_both<<<(NPIX + 255) / 256, 256, 0, stream>>>(
            nbuf0, nbuf1, osw, wsv, norm_b, norm_s, ALPHA_B, ALPHA_S);
    }

    // ---- Q0 = softmax(-U) ----
    slice_update<<<(NPIX + 255) / 256, 256, 0, stream>>>(
        U, buf0, buf1, osw, wsv, norm_b, norm_s, Q, Qh, ALPHA_B, ALPHA_S, 0);

    // ---- 5 mean-field iterations ----
    for (int it = 0; it < 5; it++) {
        gather_both_h<<<PG, 256, 0, stream>>>(Qh, offv, cntr, epw, buf0, cnt);
        uint2* a = buf0; uint2* b = buf1;
        for (int j = 0; j < DS1; j++) {   // j=0..2: both chains in one launch
            blur_both_h<<<PG, 256, 0, stream>>>(a, b,
                n1_b + (size_t)j * RB, n2_b + (size_t)j * RB,
                n1_s + (size_t)j * RS, n2_s + (size_t)j * RS, cnt);
            uint2* t = a; a = b; b = t;
        }
        for (int j = DS1; j < DB1; j++) { // j=3..5: bilateral only
            blur_b_h<<<PG, 256, 0, stream>>>(a, b, n1_b + (size_t)j * RB, n2_b + (size_t)j * RB, cnt);
            uint2* t = a; a = b; b = t;
        }
        // bilateral final in buf0, spatial final in buf1
        slice_update<<<(NPIX + 255) / 256, 256, 0, stream>>>(
            U, buf0, buf1, osw, wsv, norm_b, norm_s, Q, Qh, ALPHA_B, ALPHA_S, 1);
    }
}

// Round 12
// 980.337 us; speedup vs baseline: 1.3460x; 1.0026x over previous
//
#include <hip/hip_runtime.h>
#include <hip/hip_fp16.h>
#include <cmath>

// ---------------- problem constants ----------------
constexpr int IMH = 320, IMW = 320, NPIX = IMH * IMW, NC = 21;
constexpr int CP4 = 6;           // padded channels / 4  (24 values per row)
constexpr int DB = 5, DB1 = 6;   // bilateral lattice dim
constexpr int DS = 2, DS1 = 3;   // spatial lattice dim
constexpr int RB = NPIX * DB1;   // splat entries (bilateral) = 614400
constexpr int RS = NPIX * DS1;   // (spatial) = 307200
constexpr int TBS = 1 << 20;     // hash table slots (bilateral)
constexpr int TSS = 1 << 18;     // hash table slots (spatial)
constexpr int NBUCK = 1 << 16;   // spatial-sort buckets (c0,c1 low bytes)
constexpr int NW1 = (RB + RS) / 64;  // wave sums in the unified offset scan

// Combined lattice-value buffer layout (static partition):
//   bilateral: row 0 = sink, point m -> row m+1           (rows [0, RB])
//   spatial:   row RB+1 = sink, point m -> row RB+2+m     (rows [RB+1, ...])
// spatial neighbor n=-1 maps to RB+2+(-1) = RB+1 = sink automatically.

// epw entry packing (4B): low 17 bits = pixel index, high 15 bits = weight
// quantized to [0,32767] fixed point (abs err 3e-5 << fp16 chain rounding).

#define EMPTY_KEY 0xFFFFFFFFFFFFFFFFULL

__device__ __forceinline__ unsigned long long mix64(unsigned long long x) {
    x ^= x >> 33; x *= 0xff51afd7ed558ccdULL;
    x ^= x >> 33; x *= 0xc4ceb9fe1a85ec53ULL;
    x ^= x >> 33; return x;
}

// fp16 pack helpers: uint2 = 4 halves; math in fp32, storage fp16.
__device__ __forceinline__ float4 u2f(uint2 u) {
    __half2 a = *reinterpret_cast<__half2*>(&u.x);
    __half2 b = *reinterpret_cast<__half2*>(&u.y);
    float2 fa = __half22float2(a), fb = __half22float2(b);
    return make_float4(fa.x, fa.y, fb.x, fb.y);
}
__device__ __forceinline__ uint2 f2u(float4 v) {
    __half2 a = __floats2half2_rn(v.x, v.y);
    __half2 b = __floats2half2_rn(v.z, v.w);
    uint2 u;
    u.x = *reinterpret_cast<unsigned*>(&a);
    u.y = *reinterpret_cast<unsigned*>(&b);
    return u;
}

__device__ __forceinline__ unsigned pack_ew(int pix, float w) {
    int w15 = (int)lrintf(fminf(fmaxf(w, 0.f), 1.f) * 32767.f);
    return ((unsigned)w15 << 17) | (unsigned)pix;
}
__device__ __forceinline__ void unpack_ew(unsigned e, int& pix, float& w) {
    pix = (int)(e & 0x1FFFFu);
    w = (float)(e >> 17) * (1.0f / 32767.0f);
}

// ---------------- permutohedral embedding (matches reference op-for-op, f32) ----------------
template<int D>
__device__ void perm_embed(const float* f, float* bary, unsigned long long* pk) {
    constexpr int D1 = D + 1;
    float cf[D];
    #pragma unroll
    for (int i = 0; i < D; i++) {
        double s = sqrt(2.0 / 3.0) * (double)D1 / sqrt((double)((i + 1) * (i + 2)));
        cf[i] = f[i] * (float)s;
    }
    float csum[D];
    float acc = 0.f;
    #pragma unroll
    for (int i = D - 1; i >= 0; i--) { acc += cf[i]; csum[i] = acc; }
    float el[D1];
    el[0] = csum[0];
    #pragma unroll
    for (int i = 1; i < D; i++) el[i] = csum[i] - (float)i * cf[i - 1];
    el[D] = -(float)D * cf[D - 1];
    const float down = 1.0f / (float)D1;
    float rem0[D1]; int rank[D1]; int ssum = 0;
    #pragma unroll
    for (int i = 0; i < D1; i++) {
        float rd = rintf(el[i] * down);
        rem0[i] = rd * (float)D1;
        ssum += (int)rd;
    }
    float diff[D1];
    #pragma unroll
    for (int i = 0; i < D1; i++) diff[i] = el[i] - rem0[i];
    #pragma unroll
    for (int i = 0; i < D1; i++) {
        int r = 0;
        #pragma unroll
        for (int j = 0; j < D1; j++)
            r += (diff[j] > diff[i]) || ((diff[j] == diff[i]) && (j < i));
        rank[i] = r + ssum;
    }
    #pragma unroll
    for (int i = 0; i < D1; i++) {
        if (rank[i] < 0)      { rank[i] += D1; rem0[i] += (float)D1; }
        else if (rank[i] > D) { rank[i] -= D1; rem0[i] -= (float)D1; }
    }
    float b[D + 2];
    #pragma unroll
    for (int i = 0; i < D + 2; i++) b[i] = 0.f;
    #pragma unroll
    for (int i = 0; i < D1; i++) b[D - rank[i]]     += (el[i] - rem0[i]) * down;
    #pragma unroll
    for (int i = 0; i < D1; i++) b[D + 1 - rank[i]] -= (el[i] - rem0[i]) * down;
    b[0] += 1.0f + b[D + 1];
    #pragma unroll
    for (int i = 0; i < D1; i++) bary[i] = b[i];
    int key0[D];
    #pragma unroll
    for (int i = 0; i < D; i++) key0[i] = (int)rintf(rem0[i]);
    #pragma unroll
    for (int r = 0; r < D1; r++) {
        unsigned long long p = 0;
        #pragma unroll
        for (int i = 0; i < D; i++) {
            int c = key0[i] + ((rank[i] < D1 - r) ? r : r - D1);
            p |= ((unsigned long long)((unsigned)(c + 2048) & 0xFFFu)) << (12 * i);
        }
        pk[r] = p;
    }
}

__device__ __forceinline__ int key_code(unsigned long long k) {
    int c0 = (int)(k & 0xFFFULL);
    int c1 = (int)((k >> 12) & 0xFFFULL);
    return ((c0 & 0xFF) << 8) | (c1 & 0xFF);
}

// ---------------- hash table ----------------
// insert + bucket-histogram on CAS win (each unique key counted exactly once)
__device__ __forceinline__ int hash_insert_hist(unsigned long long* hk, int tmask,
                                                unsigned long long k, int* histbase) {
    int slot = (int)(mix64(k) & (unsigned long long)tmask);
    while (true) {
        unsigned long long prev = atomicCAS(&hk[slot], EMPTY_KEY, k);
        if (prev == EMPTY_KEY) { atomicAdd(&histbase[key_code(k)], 1); return slot; }
        if (prev == k) return slot;
        slot = (slot + 1) & tmask;
    }
}
__device__ __forceinline__ int hash_lookup(const unsigned long long* hk, const int* hid,
                                           int tmask, unsigned long long k) {
    int slot = (int)(mix64(k) & (unsigned long long)tmask);
    while (true) {
        unsigned long long v = hk[slot];
        if (v == k) return hid[slot];
        if (v == EMPTY_KEY) return -1;
        slot = (slot + 1) & tmask;
    }
}

// ---------------- build kernels ----------------
// one launch builds both lattices (hk = unified table: [0,TBS) bilateral, [TBS,+TSS) spatial)
// and accumulates the bucket histogram inline (hist halves: [0,NBUCK) b, [NBUCK,2N) s).
__global__ void build_both(const float* __restrict__ image, unsigned long long* hk,
                           int* os, float* wsv, int* hist) {
    int i = blockIdx.x * blockDim.x + threadIdx.x;
    if (i < NPIX) {
        int x = i % IMW, y = i / IMW;
        float f[DB];
        f[0] = (float)x / 80.0f;
        f[1] = (float)y / 80.0f;
        f[2] = image[i * 3 + 0] / 13.0f;
        f[3] = image[i * 3 + 1] / 13.0f;
        f[4] = image[i * 3 + 2] / 13.0f;
        float bary[DB1]; unsigned long long pk[DB1];
        perm_embed<DB>(f, bary, pk);
        #pragma unroll
        for (int r = 0; r < DB1; r++) {
            wsv[i * DB1 + r] = bary[r];
            os[i * DB1 + r] = hash_insert_hist(hk, TBS - 1, pk[r], hist);
        }
    } else if (i < 2 * NPIX) {
        int ip = i - NPIX;
        int x = ip % IMW, y = ip / IMW;
        float f[DS];
        f[0] = (float)x / 3.0f;
        f[1] = (float)y / 3.0f;
        float bary[DS1]; unsigned long long pk[DS1];
        perm_embed<DS>(f, bary, pk);
        #pragma unroll
        for (int r = 0; r < DS1; r++) {
            wsv[RB + ip * DS1 + r] = bary[r];
            os[RB + ip * DS1 + r] = hash_insert_hist(hk + TBS, TSS - 1, pk[r], hist + NBUCK);
        }
    }
}

// ---------------- barrier-free scan machinery ----------------
__global__ void scan_wave_partial(const int* __restrict__ count, int* incl, int* wsum, int n) {
    int idx = blockIdx.x * blockDim.x + threadIdx.x;
    int lane = threadIdx.x & 63;
    int v = (idx < n) ? count[idx] : 0;
    int s = v;
    #pragma unroll
    for (int d = 1; d < 64; d <<= 1) {
        int t = __shfl_up(s, d);
        if (lane >= d) s += t;
    }
    if (idx < n) incl[idx] = s;
    if (lane == 63) wsum[idx >> 6] = s;
}

__global__ void scan_partials_excl(int* w, int nw, int* total_out) {
    __shared__ int sh[256];
    __shared__ int run;
    if (threadIdx.x == 0) run = 0;
    __syncthreads();
    for (int basei = 0; basei < nw; basei += 256) {
        int idx = basei + threadIdx.x;
        int v = (idx < nw) ? w[idx] : 0;
        sh[threadIdx.x] = v;
        __syncthreads();
        for (int d = 1; d < 256; d <<= 1) {
            int t = (threadIdx.x >= d) ? sh[threadIdx.x - d] : 0;
            __syncthreads();
            sh[threadIdx.x] += t;
            __syncthreads();
        }
        int total = sh[255];
        if (idx < nw) w[idx] = run + sh[threadIdx.x] - v;
        __syncthreads();
        if (threadIdx.x == 0) run += total;
        __syncthreads();
    }
    if (total_out != nullptr && threadIdx.x == 0) *total_out = run;
}

__global__ void scan_finalize(int* off, const int* __restrict__ count,
                              const int* __restrict__ wsum, int n) {
    int idx = blockIdx.x * blockDim.x + threadIdx.x;
    if (idx < n) off[idx] = off[idx] - count[idx] + wsum[idx >> 6];
}

// ---------------- bucket-sorted compaction ----------------
__global__ void assign_both(const unsigned long long* __restrict__ hk, int* hid,
                            const int* __restrict__ histOff, int* histFill,
                            unsigned long long* uk_b, unsigned long long* uk_s) {
    int s = blockIdx.x * blockDim.x + threadIdx.x;
    if (s >= TBS + TSS) return;
    unsigned long long k = hk[s];
    if (k == EMPTY_KEY) return;
    int half = (s < TBS) ? 0 : NBUCK;
    int code = half + key_code(k);
    int id = histOff[code] + atomicAdd(&histFill[code], 1);
    hid[s] = id;
    if (s < TBS) uk_b[id] = k; else uk_s[id] = k;
}

// unified os remap + cntr histogram (cntr slots: [0,RB) bilateral ids, [RB,RB+RS) spatial)
__global__ void os_count_both(int* os, const int* __restrict__ hid, int* cntr) {
    int i = blockIdx.x * blockDim.x + threadIdx.x;
    if (i >= RB + RS) return;
    if (i < RB) {
        int id = hid[os[i]];
        os[i] = id;
        atomicAdd(&cntr[id], 1);
    } else {
        int id = hid[TBS + os[i]];
        os[i] = id;
        atomicAdd(&cntr[RB + id], 1);
    }
}

template<int D>
__global__ void build_neighbors(const unsigned long long* __restrict__ uk,
                                const unsigned long long* __restrict__ hk,
                                const int* __restrict__ hid,
                                int tmask, const int* cnt, int stride,
                                int* n1, int* n2) {
    int m = blockIdx.x * blockDim.x + threadIdx.x;
    if (m >= *cnt) return;
    unsigned long long k = uk[m];
    int c[D];
    #pragma unroll
    for (int i = 0; i < D; i++) c[i] = (int)((k >> (12 * i)) & 0xFFFULL) - 2048;
    for (int j = 0; j <= D; j++) {
        unsigned long long p1 = 0, p2 = 0;
        #pragma unroll
        for (int i = 0; i < D; i++) {
            int a = c[i] + ((i == j) ? D : -1);
            int b = c[i] + ((i == j) ? -D : 1);
            p1 |= ((unsigned long long)((unsigned)(a + 2048) & 0xFFFu)) << (12 * i);
            p2 |= ((unsigned long long)((unsigned)(b + 2048) & 0xFFFu)) << (12 * i);
        }
        n1[j * stride + m] = hash_lookup(hk, hid, tmask, p1);
        n2[j * stride + m] = hash_lookup(hk, hid, tmask, p2);
    }
}

// unified fill: epw is one packed-4B array, offsets global over RB+RS entries
__global__ void fill_both(const int* __restrict__ os, const float* __restrict__ wsv,
                          const int* __restrict__ off, int* fill, unsigned* epw) {
    int idx = blockIdx.x * blockDim.x + threadIdx.x;
    if (idx >= RB + RS) return;
    int slot, pix;
    if (idx < RB) { slot = os[idx];        pix = idx / DB1; }
    else          { slot = RB + os[idx];   pix = (idx - RB) / DS1; }
    int pos = off[slot] + atomicAdd(&fill[slot], 1);
    epw[pos] = pack_ew(pix, wsv[idx]);
}

// ---------------- batched filter kernels (fp16 storage, fp32 math) ----------------
__global__ void gather_both_h(const uint2* __restrict__ Qh, const int* __restrict__ off,
                              const int* __restrict__ cntr, const unsigned* __restrict__ epw,
                              uint2* __restrict__ buf, const int* cnt) {
    int Mb = cnt[0], Ms = cnt[1];
    int totB = (Mb + 1) * CP4;
    int tot = totB + (Ms + 1) * CP4;
    int stride = gridDim.x * blockDim.x;
    for (int idx = blockIdx.x * blockDim.x + threadIdx.x; idx < tot; idx += stride) {
        int c4, o, slot;
        if (idx < totB) {
            int row = idx / CP4; c4 = idx - row * CP4;
            o = idx;
            slot = row ? (row - 1) : -1;
        } else {
            int t = idx - totB;
            int row = t / CP4; c4 = t - row * CP4;
            o = (RB + 1 + row) * CP4 + c4;
            slot = row ? (RB + row - 1) : -1;
        }
        float4 acc = make_float4(0.f, 0.f, 0.f, 0.f);
        if (slot >= 0) {
            int s = off[slot], e = s + cntr[slot];
            for (int t = s; t < e; t++) {
                int pix; float w;
                unpack_ew(epw[t], pix, w);
                float4 v = u2f(Qh[(size_t)pix * CP4 + c4]);
                acc.x += w * v.x; acc.y += w * v.y; acc.z += w * v.z; acc.w += w * v.w;
            }
        }
        buf[o] = f2u(acc);
    }
}

__global__ void blur_both_h(const uint2* __restrict__ in, uint2* __restrict__ out,
                            const int* __restrict__ n1b, const int* __restrict__ n2b,
                            const int* __restrict__ n1s, const int* __restrict__ n2s,
                            const int* cnt) {
    int Mb = cnt[0], Ms = cnt[1];
    int totB = (Mb + 1) * CP4;
    int tot = totB + (Ms + 1) * CP4;
    int stride = gridDim.x * blockDim.x;
    for (int idx = blockIdx.x * blockDim.x + threadIdx.x; idx < tot; idx += stride) {
        if (idx < totB) {
            int row = idx / CP4, c4 = idx - row * CP4;
            if (row == 0) { out[idx] = make_uint2(0u, 0u); continue; }
            int m = row - 1;
            float4 a = u2f(in[(size_t)(n1b[m] + 1) * CP4 + c4]);
            float4 b = u2f(in[(size_t)(n2b[m] + 1) * CP4 + c4]);
            float4 x = u2f(in[idx]);
            x.x += 0.5f * (a.x + b.x); x.y += 0.5f * (a.y + b.y);
            x.z += 0.5f * (a.z + b.z); x.w += 0.5f * (a.w + b.w);
            out[idx] = f2u(x);
        } else {
            int t = idx - totB;
            int row = t / CP4, c4 = t - row * CP4;
            int o = (RB + 1 + row) * CP4 + c4;
            if (row == 0) { out[o] = make_uint2(0u, 0u); continue; }
            int m = row - 1;
            float4 a = u2f(in[(size_t)(RB + 2 + n1s[m]) * CP4 + c4]);  // -1 -> sink RB+1
            float4 b = u2f(in[(size_t)(RB + 2 + n2s[m]) * CP4 + c4]);
            float4 x = u2f(in[o]);
            x.x += 0.5f * (a.x + b.x); x.y += 0.5f * (a.y + b.y);
            x.z += 0.5f * (a.z + b.z); x.w += 0.5f * (a.w + b.w);
            out[o] = f2u(x);
        }
    }
}

__global__ void blur_b_h(const uint2* __restrict__ in, uint2* __restrict__ out,
                         const int* __restrict__ n1, const int* __restrict__ n2,
                         const int* cnt) {
    int M = cnt[0];
    int total = (M + 1) * CP4;
    int stride = gridDim.x * blockDim.x;
    for (int idx = blockIdx.x * blockDim.x + threadIdx.x; idx < total; idx += stride) {
        int row = idx / CP4, c4 = idx - row * CP4;
        if (row == 0) { out[idx] = make_uint2(0u, 0u); continue; }
        int m = row - 1;
        float4 a = u2f(in[(size_t)(n1[m] + 1) * CP4 + c4]);
        float4 b = u2f(in[(size_t)(n2[m] + 1) * CP4 + c4]);
        float4 x = u2f(in[idx]);
        x.x += 0.5f * (a.x + b.x); x.y += 0.5f * (a.y + b.y);
        x.z += 0.5f * (a.z + b.z); x.w += 0.5f * (a.w + b.w);
        out[idx] = f2u(x);
    }
}

// ---- fp32 norm-chain versions (per-row threads) ----
__global__ void gather1_both(const int* __restrict__ off, const int* __restrict__ cntr,
                             const unsigned* __restrict__ epw, float* __restrict__ buf,
                             const int* cnt) {
    int Mb = cnt[0], Ms = cnt[1];
    int totB = Mb + 1;
    int tot = totB + Ms + 1;
    int stride = gridDim.x * blockDim.x;
    for (int r = blockIdx.x * blockDim.x + threadIdx.x; r < tot; r += stride) {
        int o, slot;
        if (r < totB) { o = r;              slot = r ? (r - 1) : -1; }
        else          { int t = r - totB; o = RB + 1 + t; slot = t ? (RB + t - 1) : -1; }
        float acc = 0.f;
        if (slot >= 0) {
            int s = off[slot], e = s + cntr[slot];
            for (int t = s; t < e; t++) acc += (float)(epw[t] >> 17) * (1.0f / 32767.0f);
        }
        buf[o] = acc;
    }
}

__global__ void blur1_both(const float* __restrict__ in, float* __restrict__ out,
                           const int* __restrict__ n1b, const int* __restrict__ n2b,
                           const int* __restrict__ n1s, const int* __restrict__ n2s,
                           const int* cnt) {
    int Mb = cnt[0], Ms = cnt[1];
    int totB = Mb + 1;
    int tot = totB + Ms + 1;
    int stride = gridDim.x * blockDim.x;
    for (int r = blockIdx.x * blockDim.x + threadIdx.x; r < tot; r += stride) {
        if (r < totB) {
            if (r == 0) { out[0] = 0.f; continue; }
            int m = r - 1;
            out[r] = in[r] + 0.5f * (in[n1b[m] + 1] + in[n2b[m] + 1]);
        } else {
            int t = r - totB;
            int o = RB + 1 + t;
            if (t == 0) { out[o] = 0.f; continue; }
            int m = t - 1;
            out[o] = in[o] + 0.5f * (in[RB + 2 + n1s[m]] + in[RB + 2 + n2s[m]]);
        }
    }
}

__global__ void blur1_b(const float* __restrict__ in, float* __restrict__ out,
                        const int* __restrict__ n1, const int* __restrict__ n2,
                        const int* cnt) {
    int M = cnt[0];
    int stride = gridDim.x * blockDim.x;
    for (int row = blockIdx.x * blockDim.x + threadIdx.x; row <= M; row += stride) {
        if (row == 0) { out[0] = 0.f; continue; }
        int m = row - 1;
        out[row] = in[row] + 0.5f * (in[n1[m] + 1] + in[n2[m] + 1]);
    }
}

// both norms in one pass (bilateral final in bufB, spatial final in bufS)
__global__ void slice_norm_both(const float* __restrict__ bufB, const float* __restrict__ bufS,
                                const int* __restrict__ osw, const float* __restrict__ wsv,
                                float* __restrict__ nbv, float* __restrict__ nsv,
                                float alphaB, float alphaS) {
    int i = blockIdx.x * blockDim.x + threadIdx.x;
    if (i >= NPIX) return;
    float sb = 0.f;
    #pragma unroll
    for (int r = 0; r < DB1; r++)
        sb += wsv[i * DB1 + r] * bufB[osw[i * DB1 + r] + 1];
    float ss = 0.f;
    #pragma unroll
    for (int r = 0; r < DS1; r++)
        ss += wsv[RB + i * DS1 + r] * bufS[RB + 2 + osw[RB + i * DS1 + r]];
    nbv[i] = alphaB * sb + 1e-20f;
    nsv[i] = alphaS * ss + 1e-20f;
}

// fused: slice(bilateral)+slice(spatial)+normalize+softmax -> Q (fp32) + Qh (fp16)
__global__ void slice_update(const float* __restrict__ U,
                             const uint2* __restrict__ bufB, const uint2* __restrict__ bufS,
                             const int* __restrict__ osw, const float* __restrict__ wsv,
                             const float* __restrict__ nbv, const float* __restrict__ nsv,
                             float* __restrict__ Q, uint2* __restrict__ Qh,
                             float alphaB, float alphaS, int use_msg) {
    int i = blockIdx.x * blockDim.x + threadIdx.x;
    if (i >= NPIX) return;
    float msg[24];
    #pragma unroll
    for (int t = 0; t < 24; t++) msg[t] = 0.f;
    if (use_msg) {
        float ib = 10.0f * alphaB / nbv[i];
        float is = 3.0f * alphaS / nsv[i];
        #pragma unroll
        for (int r = 0; r < DB1; r++) {
            float w = ib * wsv[i * DB1 + r];
            size_t base = (size_t)(osw[i * DB1 + r] + 1) * CP4;
            #pragma unroll
            for (int t = 0; t < CP4; t++) {
                float4 v = u2f(bufB[base + t]);
                msg[4 * t + 0] += w * v.x; msg[4 * t + 1] += w * v.y;
                msg[4 * t + 2] += w * v.z; msg[4 * t + 3] += w * v.w;
            }
        }
        #pragma unroll
        for (int r = 0; r < DS1; r++) {
            float w = is * wsv[RB + i * DS1 + r];
            size_t base = (size_t)(RB + 2 + osw[RB + i * DS1 + r]) * CP4;
            #pragma unroll
            for (int t = 0; t < CP4; t++) {
                float4 v = u2f(bufS[base + t]);
                msg[4 * t + 0] += w * v.x; msg[4 * t + 1] += w * v.y;
                msg[4 * t + 2] += w * v.z; msg[4 * t + 3] += w * v.w;
            }
        }
    }
    float mx = -1e30f;
    #pragma unroll
    for (int c = 0; c < NC; c++) {
        msg[c] = -U[i * NC + c] + msg[c];
        mx = fmaxf(mx, msg[c]);
    }
    float s = 0.f;
    #pragma unroll
    for (int c = 0; c < NC; c++) { float e = expf(msg[c] - mx); msg[c] = e; s += e; }
    float inv = 1.0f / s;
    #pragma unroll
    for (int c = 0; c < NC; c++) {
        msg[c] *= inv;
        Q[i * NC + c] = msg[c];
    }
    msg[21] = 0.f; msg[22] = 0.f; msg[23] = 0.f;
    #pragma unroll
    for (int t = 0; t < CP4; t++)
        Qh[i * CP4 + t] = f2u(make_float4(msg[4 * t], msg[4 * t + 1], msg[4 * t + 2], msg[4 * t + 3]));
}

// ---------------- host orchestration ----------------
extern "C" void kernel_launch(void* const* d_in, const int* in_sizes, int n_in,
                              void* d_out, int out_size, void* d_ws, size_t ws_size,
                              hipStream_t stream) {
    const float* U     = (const float*)d_in[0];
    const float* image = (const float*)d_in[1];
    float* Q = (float*)d_out;

    char* base = (char*)d_ws;
    size_t off = 0;
    auto alloc = [&](size_t bytes) -> void* {
        off = (off + 255) & ~(size_t)255;
        void* p = base + off; off += bytes; return p;
    };
    // unified per-entry arrays: [0,RB) bilateral, [RB,RB+RS) spatial
    int*   osw  = (int*)  alloc((size_t)(RB + RS) * 4);
    float* wsv  = (float*)alloc((size_t)(RB + RS) * 4);
    int*   n1_b = (int*)  alloc((size_t)DB1 * RB * 4);
    int*   n2_b = (int*)  alloc((size_t)DB1 * RB * 4);
    int*   n1_s = (int*)  alloc((size_t)DS1 * RS * 4);
    int*   n2_s = (int*)  alloc((size_t)DS1 * RS * 4);
    unsigned long long* uk_b = (unsigned long long*)alloc((size_t)RB * 8);
    unsigned long long* uk_s = (unsigned long long*)alloc((size_t)RS * 8);
    unsigned long long* hk = (unsigned long long*)alloc((size_t)(TBS + TSS) * 8);
    int*   hid  = (int*)  alloc((size_t)(TBS + TSS) * 4);
    int*   cnt  = (int*)  alloc(256);   // [0]=M_b, [1]=M_s
    int*   histOff = (int*)alloc((size_t)2 * NBUCK * 4);
    int*   wsums   = (int*)alloc((size_t)64 * 1024 * 4);
    int*   wsI     = (int*)alloc((size_t)16384 * 4);   // level-1 inclusive sums
    int*   ws2     = (int*)alloc((size_t)1024 * 4);    // level-2 sums
    int*   offv    = (int*)alloc((size_t)(RB + RS) * 4);
    // contiguous zero region: cntr | fill | hist | histFill
    char*  zreg  = (char*)alloc((size_t)(RB + RS) * 8 + (size_t)2 * NBUCK * 8);
    int*   cntr     = (int*)zreg;
    int*   fill     = cntr + (RB + RS);
    int*   hist     = fill + (RB + RS);
    int*   histFill = hist + 2 * NBUCK;
    size_t zbytes = (size_t)(RB + RS) * 8 + (size_t)2 * NBUCK * 8;
    unsigned* epw = (unsigned*)alloc((size_t)(RB + RS) * 4);   // packed 4B entries
    float* norm_b = (float*)alloc((size_t)NPIX * 4);
    float* norm_s = (float*)alloc((size_t)NPIX * 4);
    uint2* Qh   = (uint2*)alloc((size_t)NPIX * CP4 * 8);
    // combined lattice buffers: rows RB+RS+2 (bilateral [0,RB], spatial [RB+1,...])
    uint2* buf0 = (uint2*)alloc((size_t)(RB + RS + 2) * CP4 * 8);
    uint2* buf1 = (uint2*)alloc((size_t)(RB + RS + 2) * CP4 * 8);
    float* nbuf0 = (float*)alloc((size_t)(RB + RS + 2) * 4);
    float* nbuf1 = (float*)alloc((size_t)(RB + RS + 2) * 4);
    if (off > ws_size) return;

    const float ALPHA_B = (float)(1.0 / (1.0 + exp2(-(double)DB)));  // 32/33
    const float ALPHA_S = (float)(1.0 / (1.0 + exp2(-(double)DS)));  // 4/5

    constexpr int PG = 4096;

    // ---- 3 memsets ----
    hipMemsetAsync(cnt, 0, 16, stream);
    hipMemsetAsync(hk, 0xFF, (size_t)(TBS + TSS) * 8, stream);
    hipMemsetAsync(zreg, 0, zbytes, stream);

    // ---- build both lattices (histogram fused into insertion) ----
    build_both<<<(2 * NPIX + 255) / 256, 256, 0, stream>>>(image, hk, osw, wsv, hist);
    // compaction scans per table (ids start at 0 for each)
    scan_wave_partial<<<NBUCK / 256, 256, 0, stream>>>(hist, histOff, wsums, NBUCK);
    scan_partials_excl<<<1, 256, 0, stream>>>(wsums, NBUCK / 64, cnt + 0);
    scan_finalize<<<NBUCK / 256, 256, 0, stream>>>(histOff, hist, wsums, NBUCK);
    scan_wave_partial<<<NBUCK / 256, 256, 0, stream>>>(hist + NBUCK, histOff + NBUCK, wsums, NBUCK);
    scan_partials_excl<<<1, 256, 0, stream>>>(wsums, NBUCK / 64, cnt + 1);
    scan_finalize<<<NBUCK / 256, 256, 0, stream>>>(histOff + NBUCK, hist + NBUCK, wsums, NBUCK);
    assign_both<<<(TBS + TSS) / 256, 256, 0, stream>>>(hk, hid, histOff, histFill, uk_b, uk_s);
    os_count_both<<<(RB + RS) / 256, 256, 0, stream>>>(osw, hid, cntr);
    build_neighbors<DB><<<(RB + 255) / 256, 256, 0, stream>>>(uk_b, hk, hid, TBS - 1, cnt + 0, RB, n1_b, n2_b);
    build_neighbors<DS><<<(RS + 255) / 256, 256, 0, stream>>>(uk_s, hk + TBS, hid + TBS, TSS - 1, cnt + 1, RS, n1_s, n2_s);
    // unified offset scan over RB+RS id slots — hierarchical
    scan_wave_partial<<<(RB + RS) / 256, 256, 0, stream>>>(cntr, offv, wsums, RB + RS);
    scan_wave_partial<<<(NW1 + 255) / 256, 256, 0, stream>>>(wsums, wsI, ws2, NW1);
    scan_partials_excl<<<1, 256, 0, stream>>>(ws2, (NW1 + 63) / 64, nullptr);
    scan_finalize<<<(NW1 + 255) / 256, 256, 0, stream>>>(wsI, wsums, ws2, NW1);
    scan_finalize<<<(RB + RS) / 256, 256, 0, stream>>>(offv, cntr, wsI, RB + RS);
    fill_both<<<(RB + RS + 255) / 256, 256, 0, stream>>>(osw, wsv, offv, fill, epw);

    // ---- norm filters (C=1, fp32), batched ----
    {
        gather1_both<<<1024, 256, 0, stream>>>(offv, cntr, epw, nbuf0, cnt);
        float* a = nbuf0; float* b = nbuf1;
        for (int j = 0; j < DS1; j++) {   // j=0..2: both chains
            blur1_both<<<1024, 256, 0, stream>>>(a, b,
                n1_b + (size_t)j * RB, n2_b + (size_t)j * RB,
                n1_s + (size_t)j * RS, n2_s + (size_t)j * RS, cnt);
            float* t = a; a = b; b = t;
        }
        // j=3..5: bilateral only — writes only rows [0,Mb]; spatial final stays in nbuf1.
        for (int j = DS1; j < DB1; j++) {
            blur1_b<<<1024, 256, 0, stream>>>(a, b, n1_b + (size_t)j * RB, n2_b + (size_t)j * RB, cnt);
            float* t = a; a = b; b = t;
        }
        // bilateral final in nbuf0 (6 swaps), spatial final in nbuf1 (3 swaps)
        slice_norm_both<<<(NPIX + 255) / 256, 256, 0, stream>>>(
            nbuf0, nbuf1, osw, wsv, norm_b, norm_s, ALPHA_B, ALPHA_S);
    }

    // ---- Q0 = softmax(-U) ----
    slice_update<<<(NPIX + 255) / 256, 256, 0, stream>>>(
        U, buf0, buf1, osw, wsv, norm_b, norm_s, Q, Qh, ALPHA_B, ALPHA_S, 0);

    // ---- 5 mean-field iterations ----
    for (int it = 0; it < 5; it++) {
        gather_both_h<<<PG, 256, 0, stream>>>(Qh, offv, cntr, epw, buf0, cnt);
        uint2* a = buf0; uint2* b = buf1;
        for (int j = 0; j < DS1; j++) {   // j=0..2: both chains in one launch
            blur_both_h<<<PG, 256, 0, stream>>>(a, b,
                n1_b + (size_t)j * RB, n2_b + (size_t)j * RB,
                n1_s + (size_t)j * RS, n2_s + (size_t)j * RS, cnt);
            uint2* t = a; a = b; b = t;
        }
        for (int j = DS1; j < DB1; j++) { // j=3..5: bilateral only
            blur_b_h<<<PG, 256, 0, stream>>>(a, b, n1_b + (size_t)j * RB, n2_b + (size_t)j * RB, cnt);
            uint2* t = a; a = b; b = t;
        }
        // bilateral final in buf0, spatial final in buf1
        slice_update<<<(NPIX + 255) / 256, 256, 0, stream>>>(
            U, buf0, buf1, osw, wsv, norm_b, norm_s, Q, Qh, ALPHA_B, ALPHA_S, 1);
    }
}